// Round 12
// baseline (419.163 us; speedup 1.0000x reference)
//
#include <hip/hip_runtime.h>
#include <hip/hip_bf16.h>

// Mamba2 block forward. B=4 L=4096 D_MODEL=512 D_INNER=2048 H=8 P=256 N=64
// CHUNK=256 C=16 CONV_DIM=2176.
// Round 12: ssd_y v3 — (a) separate Wl LDS buffer removes one barrier per
// stile (4->3); (b) T14 async-STAGE: next stile's X/b loads issued to regs
// before W+Y compute, ds_written after the Y barrier (latency hidden under
// ~40 MFMA). LDS 57.9KB -> 2 blocks/CU (8 waves >= current 7). Rest = r11.

#define BB 4
#define LL 4096
#define DM 512
#define DI 2048
#define NH 8
#define HD 256
#define DS 64
#define DCONV 4
#define CHK 256
#define NC 16
#define CONVD 2176
#define MROWS (BB*LL)    // 16384
#define ZXW (DI + CONVD) // 4224

typedef __hip_bfloat16 bf16;
typedef short s8 __attribute__((ext_vector_type(8)));   // 8 bf16 (4 VGPRs)
typedef float f4 __attribute__((ext_vector_type(4)));   // MFMA acc

__device__ __forceinline__ f4 mfma16(s8 a, s8 b, f4 c) {
    return __builtin_amdgcn_mfma_f32_16x16x32_bf16(a, b, c, 0, 0, 0);
}

__device__ __forceinline__ void gload16(const bf16* g, bf16* l) {
    __builtin_amdgcn_global_load_lds(
        (const __attribute__((address_space(1))) void*)g,
        (__attribute__((address_space(3))) void*)l, 16, 0, 0);
}

__device__ __forceinline__ float ldf(const float* p) { return *p; }
__device__ __forceinline__ float ldf(const bf16* p) { return __bfloat162float(*p); }
__device__ __forceinline__ void stf(float* p, float v) { *p = v; }
__device__ __forceinline__ void stf(bf16* p, float v) { *p = __float2bfloat16(v); }

// ---------------- f32 -> bf16 cast (8/thread) ----------------
__global__ void cast_bf16_kernel(const float* __restrict__ in, bf16* __restrict__ out) {
    long i8 = ((long)blockIdx.x * 256 + threadIdx.x) * 8;
    float4 a = *(const float4*)&in[i8];
    float4 b = *(const float4*)&in[i8 + 4];
    bf16 v[8];
    v[0] = __float2bfloat16(a.x); v[1] = __float2bfloat16(a.y);
    v[2] = __float2bfloat16(a.z); v[3] = __float2bfloat16(a.w);
    v[4] = __float2bfloat16(b.x); v[5] = __float2bfloat16(b.y);
    v[6] = __float2bfloat16(b.z); v[7] = __float2bfloat16(b.w);
    *(uint4*)&out[i8] = *(uint4*)v;
}

// ---------------- f32 [K][N] -> bf16 [N][K] transpose-cast (weights) ----------------
__global__ void tcast_kernel(const float* __restrict__ in, bf16* __restrict__ out,
                             int K, int N) {
    __shared__ float tile[64][65];
    int t = threadIdx.x;
    int n0 = blockIdx.x * 64, k0 = blockIdx.y * 64;
#pragma unroll
    for (int i = 0; i < 16; i++) {
        int u = t + i * 256; int kr = u >> 6, nc = u & 63;
        tile[kr][nc] = in[(long)(k0 + kr) * N + n0 + nc];
    }
    __syncthreads();
#pragma unroll
    for (int i = 0; i < 16; i++) {
        int u = t + i * 256; int nr = u >> 6, kc = u & 63;
        out[(long)(n0 + nr) * K + k0 + kc] = __float2bfloat16(tile[kc][nr]);
    }
}

// ---------------- gemm_sb: single-buffered 128^2, 4 blocks/CU ----------------
template <typename TC>
__global__ __launch_bounds__(256, 4) void gemm_sb(const bf16* __restrict__ A,
                                                  const bf16* __restrict__ BT,
                                                  TC* __restrict__ C, int N, int K,
                                                  int lda, int ldc) {
    __shared__ __align__(16) char smem[34816];  // staging 32KB | bf16 C-epilogue 34KB
    bf16 (*At)[64] = (bf16(*)[64])smem;
    bf16 (*Bt)[64] = (bf16(*)[64])(smem + 16384);
    const int t = threadIdx.x, lane = t & 63, w = t >> 6;
    const int wr = w >> 1, wc = w & 1;
    const int bid = blockIdx.x;
    const int idx = bid >> 3;
    const int mt = (bid & 7) * 16 + (idx & 15);   // nMt = 128 fixed
    const int nt = idx >> 4;
    const long m0 = (long)mt * 128;
    const int n0 = nt * 128;
    const int lrow = lane >> 3, lblk = lane & 7;
    f4 acc[4][4];
#pragma unroll
    for (int mi = 0; mi < 4; mi++)
#pragma unroll
        for (int ni = 0; ni < 4; ni++) acc[mi][ni] = (f4){0.f, 0.f, 0.f, 0.f};

    for (int k0 = 0; k0 < K; k0 += 64) {
#pragma unroll
        for (int i = 0; i < 4; i++) {
            int rbase = w * 32 + i * 8;
            int row = rbase + lrow;
            int kb = (lblk ^ (row & 7)) << 3;   // source k-block, pre-swizzled
            gload16(&A[(m0 + row) * (long)lda + k0 + kb], &At[rbase][0]);
            gload16(&BT[((long)n0 + row) * K + k0 + kb], &Bt[rbase][0]);
        }
        __syncthreads();
        __builtin_amdgcn_s_setprio(1);
#pragma unroll
        for (int ks = 0; ks < 2; ks++) {
            int k8 = ks * 4 + (lane >> 4);
            s8 af[4], bfr[4];
#pragma unroll
            for (int mi = 0; mi < 4; mi++) {
                int row = wr * 64 + mi * 16 + (lane & 15);
                af[mi] = *(const s8*)&At[row][(k8 ^ (row & 7)) << 3];
            }
#pragma unroll
            for (int ni = 0; ni < 4; ni++) {
                int row = wc * 64 + ni * 16 + (lane & 15);
                bfr[ni] = *(const s8*)&Bt[row][(k8 ^ (row & 7)) << 3];
            }
#pragma unroll
            for (int mi = 0; mi < 4; mi++)
#pragma unroll
                for (int ni = 0; ni < 4; ni++)
                    acc[mi][ni] = mfma16(af[mi], bfr[ni], acc[mi][ni]);
        }
        __builtin_amdgcn_s_setprio(0);
        __syncthreads();
    }
    if constexpr (sizeof(TC) == 2) {
        bf16 (*Ct)[136] = (bf16(*)[136])smem;
#pragma unroll
        for (int mi = 0; mi < 4; mi++)
#pragma unroll
            for (int ni = 0; ni < 4; ni++)
#pragma unroll
                for (int r = 0; r < 4; r++)
                    Ct[wr * 64 + mi * 16 + (lane >> 4) * 4 + r]
                      [wc * 64 + ni * 16 + (lane & 15)] =
                        __float2bfloat16(acc[mi][ni][r]);
        __syncthreads();
#pragma unroll
        for (int i = 0; i < 8; i++) {
            int u = t + i * 256; int row = u >> 4, j = u & 15;
            *(uint4*)&C[(m0 + row) * (long)ldc + n0 + j * 8] = *(uint4*)&Ct[row][j * 8];
        }
    } else {
#pragma unroll
        for (int mi = 0; mi < 4; mi++)
#pragma unroll
            for (int ni = 0; ni < 4; ni++)
#pragma unroll
                for (int r = 0; r < 4; r++)
                    stf(&C[(m0 + wr * 64 + mi * 16 + (lane >> 4) * 4 + r) * (long)ldc +
                           n0 + wc * 64 + ni * 16 + (lane & 15)], acc[mi][ni][r]);
    }
}

// ---------------- gemm_db: 2-phase dbuf 128^2 — used for Wout (K=2048) ----------------
template <typename TC>
__global__ __launch_bounds__(256) void gemm_db(const bf16* __restrict__ A,
                                               const bf16* __restrict__ BT,
                                               TC* __restrict__ C, int N, int K,
                                               int lda, int ldc) {
    __shared__ __align__(16) char smem[65536];
    bf16 (*At)[128][64] = (bf16(*)[128][64])smem;
    bf16 (*Bt)[128][64] = (bf16(*)[128][64])(smem + 32768);
    const int t = threadIdx.x, lane = t & 63, w = t >> 6;
    const int wr = w >> 1, wc = w & 1;
    const int bid = blockIdx.x;
    const int idx = bid >> 3;
    const int nNt = N >> 7;
    const int nt = idx % nNt;                       // nt fastest
    const int mt = (bid & 7) * 16 + (idx / nNt);    // nMt = 128 fixed
    const long m0 = (long)mt * 128;
    const int n0 = nt * 128;
    const int lrow = lane >> 3, lblk = lane & 7;
    const int KT = K >> 6;
    f4 acc[4][4];
#pragma unroll
    for (int mi = 0; mi < 4; mi++)
#pragma unroll
        for (int ni = 0; ni < 4; ni++) acc[mi][ni] = (f4){0.f, 0.f, 0.f, 0.f};

    auto STAGE = [&](int bu, int kt) {
        int k0 = kt << 6;
#pragma unroll
        for (int i = 0; i < 4; i++) {
            int rbase = w * 32 + i * 8;
            int row = rbase + lrow;
            int kb = (lblk ^ (row & 7)) << 3;
            gload16(&A[(m0 + row) * (long)lda + k0 + kb], &At[bu][rbase][0]);
            gload16(&BT[((long)n0 + row) * K + k0 + kb], &Bt[bu][rbase][0]);
        }
    };

    STAGE(0, 0);
    int bu = 0;
    for (int kt = 0; kt < KT; kt++) {
        if (kt + 1 < KT) {
            STAGE(bu ^ 1, kt + 1);
            asm volatile("s_waitcnt vmcnt(8)" ::: "memory");
        } else {
            asm volatile("s_waitcnt vmcnt(0)" ::: "memory");
        }
        __builtin_amdgcn_sched_barrier(0);
        __builtin_amdgcn_s_barrier();
        __builtin_amdgcn_s_setprio(1);
#pragma unroll
        for (int ks = 0; ks < 2; ks++) {
            int k8 = ks * 4 + (lane >> 4);
            s8 af[4], bfr[4];
#pragma unroll
            for (int mi = 0; mi < 4; mi++) {
                int row = wr * 64 + mi * 16 + (lane & 15);
                af[mi] = *(const s8*)&At[bu][row][(k8 ^ (row & 7)) << 3];
            }
#pragma unroll
            for (int ni = 0; ni < 4; ni++) {
                int row = wc * 64 + ni * 16 + (lane & 15);
                bfr[ni] = *(const s8*)&Bt[bu][row][(k8 ^ (row & 7)) << 3];
            }
#pragma unroll
            for (int mi = 0; mi < 4; mi++)
#pragma unroll
                for (int ni = 0; ni < 4; ni++)
                    acc[mi][ni] = mfma16(af[mi], bfr[ni], acc[mi][ni]);
        }
        __builtin_amdgcn_s_setprio(0);
        __builtin_amdgcn_s_barrier();
        bu ^= 1;
    }
    __syncthreads();
    if constexpr (sizeof(TC) == 2) {
        bf16 (*Ct)[136] = (bf16(*)[136])smem;
#pragma unroll
        for (int mi = 0; mi < 4; mi++)
#pragma unroll
            for (int ni = 0; ni < 4; ni++)
#pragma unroll
                for (int r = 0; r < 4; r++)
                    Ct[wr * 64 + mi * 16 + (lane >> 4) * 4 + r]
                      [wc * 64 + ni * 16 + (lane & 15)] =
                        __float2bfloat16(acc[mi][ni][r]);
        __syncthreads();
#pragma unroll
        for (int i = 0; i < 8; i++) {
            int u = t + i * 256; int row = u >> 4, j = u & 15;
            *(uint4*)&C[(m0 + row) * (long)ldc + n0 + j * 8] = *(uint4*)&Ct[row][j * 8];
        }
    } else {
#pragma unroll
        for (int mi = 0; mi < 4; mi++)
#pragma unroll
            for (int ni = 0; ni < 4; ni++)
#pragma unroll
                for (int r = 0; r < 4; r++)
                    stf(&C[(m0 + wr * 64 + mi * 16 + (lane >> 4) * 4 + r) * (long)ldc +
                           n0 + wc * 64 + ni * 16 + (lane & 15)], acc[mi][ni][r]);
    }
}

// ---------------- dt = softplus(inputs @ Wdt + bias) ----------------
__global__ void dt_kernel(const float* __restrict__ inp, const float* __restrict__ Wdt,
                          const float* __restrict__ dt_bias, float* __restrict__ dtb) {
    __shared__ float wlds[DM * NH];  // 16 KB
    int t = threadIdx.x;
#pragma unroll
    for (int i = 0; i < 16; i++) wlds[t + i * 256] = Wdt[t + i * 256];
    __syncthreads();
    int idx = blockIdx.x * 256 + t;
    int h = idx & 7;
    long row = idx >> 3;
    const float* ir = inp + row * DM;
    float acc = 0.f;
    for (int k = 0; k < DM; k += 4) {
        float4 a = *(const float4*)&ir[k];
        acc += a.x * wlds[k * 8 + h] + a.y * wlds[(k + 1) * 8 + h]
             + a.z * wlds[(k + 2) * 8 + h] + a.w * wlds[(k + 3) * 8 + h];
    }
    acc += dt_bias[h];
    float sp = acc > 20.f ? acc : log1pf(expf(acc));
    dtb[idx] = sp;
}

// ---------------- conv_x: conv(4)+silu+*dt over x channels, writes xdtT ----------------
__global__ __launch_bounds__(256) void conv_x(const bf16* __restrict__ zxbc,
                                              const float* __restrict__ ck,
                                              const float* __restrict__ dtb,
                                              bf16* __restrict__ xdtT) {
    __shared__ __align__(16) bf16 in_lds[67][72];
    __shared__ __align__(16) bf16 out_lds[64][64];
    __shared__ float dts[64];
    const int bid = blockIdx.x;
    const int ct = bid & 31, lt = (bid >> 5) & 63, b = bid >> 11;
    const int t = threadIdx.x;
    const int l0 = lt * 64;
    const long brow = (long)b * LL;
    const int h = ct >> 2;

#pragma unroll
    for (int i = 0; i < 3; i++) {
        int u = t + i * 256;
        if (u < 536) {
            int r = u >> 3, c8 = (u & 7) * 8;
            int gl = l0 - 3 + r;
            uint4 v = (gl >= 0)
                ? *(const uint4*)&zxbc[(brow + gl) * ZXW + DI + ct * 64 + c8]
                : (uint4){0, 0, 0, 0};
            *(uint4*)&in_lds[r][c8] = v;
        }
    }
    if (t < 64) dts[t] = dtb[(brow + l0 + t) * NH + h];
    __syncthreads();

    const int ch = t & 63, w = t >> 6;
    const int gch = ct * 64 + ch;
    float k0 = ck[0 * CONVD + gch], k1 = ck[1 * CONVD + gch];
    float k2 = ck[2 * CONVD + gch], k3 = ck[3 * CONVD + gch];
    float w0 = __bfloat162float(in_lds[w * 16 + 0][ch]);
    float w1 = __bfloat162float(in_lds[w * 16 + 1][ch]);
    float w2 = __bfloat162float(in_lds[w * 16 + 2][ch]);
    bf16 o[16];
#pragma unroll
    for (int i = 0; i < 16; i++) {
        float w3 = __bfloat162float(in_lds[w * 16 + i + 3][ch]);
        float v = w0 * k0 + w1 * k1 + w2 * k2 + w3 * k3;
        float s = v / (1.f + __expf(-v));
        o[i] = __float2bfloat16(s * dts[w * 16 + i]);
        w0 = w1; w1 = w2; w2 = w3;
    }
#pragma unroll
    for (int j = 0; j < 2; j++) {
        int blk = w * 2 + j;
        *(uint4*)&out_lds[ch][((blk ^ (ch & 7)) << 3)] = *(uint4*)&o[j * 8];
    }
    __syncthreads();
#pragma unroll
    for (int i = 0; i < 2; i++) {
        int u = t + i * 256;
        int chr = u >> 3, l8 = u & 7;
        uint4 v = *(const uint4*)&out_lds[chr][((l8 ^ (chr & 7)) << 3)];
        *(uint4*)&xdtT[((long)b * DI + ct * 64 + chr) * LL + l0 + l8 * 8] = v;
    }
}

// ---------------- conv_bc: conv+silu for b/c channels ----------------
__global__ void conv_bc(const bf16* __restrict__ zxbc, const float* __restrict__ ck,
                        bf16* __restrict__ bm, bf16* __restrict__ cm) {
    long idx = (long)blockIdx.x * 256 + threadIdx.x;
    if (idx >= (long)MROWS * 128 / 8) return;
    long e0 = idx * 8;
    int ch = (int)(e0 & 127);
    long bl = e0 >> 7;
    int l = (int)(bl & (LL - 1));
    float acc[8] = {};
#pragma unroll
    for (int k = 0; k < DCONV; k++) {
        int ls = l - 3 + k;
        if (ls >= 0) {
            bf16 v[8];
            *(uint4*)v = *(const uint4*)&zxbc[(bl - l + ls) * ZXW + 2 * DI + ch];
            float4 c0 = *(const float4*)&ck[k * CONVD + DI + ch];
            float4 c1 = *(const float4*)&ck[k * CONVD + DI + ch + 4];
            acc[0] += __bfloat162float(v[0]) * c0.x;
            acc[1] += __bfloat162float(v[1]) * c0.y;
            acc[2] += __bfloat162float(v[2]) * c0.z;
            acc[3] += __bfloat162float(v[3]) * c0.w;
            acc[4] += __bfloat162float(v[4]) * c1.x;
            acc[5] += __bfloat162float(v[5]) * c1.y;
            acc[6] += __bfloat162float(v[6]) * c1.z;
            acc[7] += __bfloat162float(v[7]) * c1.w;
        }
    }
    bf16 o[8];
#pragma unroll
    for (int j = 0; j < 8; j++) {
        float s = acc[j] / (1.f + __expf(-acc[j]));
        o[j] = __float2bfloat16(s);
    }
    if (ch < DS) *(uint4*)&bm[bl * DS + ch] = *(uint4*)o;
    else         *(uint4*)&cm[bl * DS + (ch - DS)] = *(uint4*)o;
}

// ---------------- per-(b,h,c) cumsum of a*dt ----------------
__global__ void cumsum_kernel(const float* __restrict__ dtb, const float* __restrict__ a_log,
                              float* __restrict__ cumA, float* __restrict__ csum) {
    int t = blockIdx.x * 256 + threadIdx.x;  // t = b*128 + h*16 + c
    if (t >= BB * NH * NC) return;
    int c = t & 15, h = (t >> 4) & 7, b = t >> 7;
    float a = -expf(a_log[h]);
    long base_l = (long)b * LL + (long)c * CHK;
    float s = 0.f;
    long obase = (long)t * CHK;
    for (int i = 0; i < CHK; i++) {
        s += a * dtb[(base_l + i) * NH + h];
        cumA[obase + i] = s;
    }
    csum[t] = s;
}

// ---------------- states via MFMA: st[p][n] = sum_l x[l,p]*b[l,n]*dec[l] ----------------
__global__ __launch_bounds__(256, 4) void states_mfma(
        const bf16* __restrict__ bmat, const bf16* __restrict__ xdtT,
        const float* __restrict__ cumA, const float* __restrict__ csum,
        bf16* __restrict__ st) {
    __shared__ __align__(16) bf16 XT[256][72];
    __shared__ __align__(16) bf16 BT[64][72];
    const int z = blockIdx.x;  // b*128 + c*8 + h
    const int h = z & 7, c = (z >> 3) & 15, b = z >> 7;
    const long blr = (long)b * LL + (long)c * CHK;
    const int bhc = (b * NH + h) * NC + c;
    const float A = csum[bhc];
    const int t = threadIdx.x, lane = t & 63, w = t >> 6;
    const bf16* xrow = xdtT + ((long)b * DI + h * HD) * LL + c * CHK;
    f4 acc[4][4];
#pragma unroll
    for (int mi = 0; mi < 4; mi++)
#pragma unroll
        for (int ni = 0; ni < 4; ni++) acc[mi][ni] = (f4){0.f, 0.f, 0.f, 0.f};

    for (int lt = 0; lt < 4; lt++) {
        const int l0 = lt * 64;
#pragma unroll
        for (int i = 0; i < 2; i++) {
            int u = t + i * 256; int l = u >> 3, n8 = (u & 7) * 8;
            bf16 v[8];
            *(uint4*)v = *(const uint4*)&bmat[(blr + l0 + l) * DS + n8];
            float d = __expf(A - cumA[(long)bhc * CHK + l0 + l]);
#pragma unroll
            for (int j = 0; j < 8; j++) {
                int n = n8 + j;
                BT[n][l ^ ((n & 7) << 3)] = __float2bfloat16(__bfloat162float(v[j]) * d);
            }
        }
#pragma unroll
        for (int i = 0; i < 8; i++) {
            int u = t + i * 256; int pp = u >> 3, s8v = u & 7;
            *(uint4*)&XT[pp][s8v * 8] =
                *(const uint4*)&xrow[(long)pp * LL + l0 + ((s8v ^ (pp & 7)) << 3)];
        }
        __syncthreads();
        __builtin_amdgcn_s_setprio(1);
#pragma unroll
        for (int ks = 0; ks < 2; ks++) {
            int col = ks * 32 + (lane >> 4) * 8;
            s8 af[4], bx[4];
#pragma unroll
            for (int mi = 0; mi < 4; mi++) {
                int n = mi * 16 + (lane & 15);
                af[mi] = *(const s8*)&BT[n][col ^ ((n & 7) << 3)];
            }
#pragma unroll
            for (int ni = 0; ni < 4; ni++) {
                int p = w * 64 + ni * 16 + (lane & 15);
                bx[ni] = *(const s8*)&XT[p][col ^ ((p & 7) << 3)];
            }
#pragma unroll
            for (int mi = 0; mi < 4; mi++)
#pragma unroll
                for (int ni = 0; ni < 4; ni++)
                    acc[mi][ni] = mfma16(af[mi], bx[ni], acc[mi][ni]);
        }
        __builtin_amdgcn_s_setprio(0);
        __syncthreads();
    }
    bf16* so = st + (long)z * (HD * DS);
#pragma unroll
    for (int mi = 0; mi < 4; mi++)
#pragma unroll
        for (int ni = 0; ni < 4; ni++) {
            int p = w * 64 + ni * 16 + (lane & 15);
            int n0 = mi * 16 + (lane >> 4) * 4;
            bf16 vv[4];
#pragma unroll
            for (int r = 0; r < 4; r++) vv[r] = __float2bfloat16(acc[mi][ni][r]);
            *(uint2*)&so[p * 64 + n0] = *(uint2*)vv;
        }
}

// ---------------- serial chunk scan (in place, bf16, f32 accum in regs) ----------------
__global__ void scan_kernel(bf16* __restrict__ st, const float* __restrict__ csum) {
    long idx = (long)blockIdx.x * 256 + threadIdx.x;
    int pn = (int)(idx & 16383);
    int h = (int)((idx >> 14) & 7);
    int b = (int)(idx >> 17);
    float S = 0.f;
    for (int c = 0; c < NC; c++) {
        long si = (((long)(b * NC + c) * NH + h) * (HD * DS)) + pn;
        float chunk = __bfloat162float(st[si]);
        st[si] = __float2bfloat16(S);
        S = S * __expf(csum[(b * NH + h) * NC + c]) + chunk;
    }
}

// ---------------- fused SSD y via MFMA (v3: Wl buffer + async-STAGE) ----------------
__global__ __launch_bounds__(256, 2) void ssd_y_mfma(
        const bf16* __restrict__ bmat, const bf16* __restrict__ cmat,
        const bf16* __restrict__ xdtT, const bf16* __restrict__ st,
        const float* __restrict__ cumA, bf16* __restrict__ y, int ldy) {
    __shared__ __align__(16) bf16 cT[64][64];
    __shared__ __align__(16) bf16 bW[64][64];    // b-tile
    __shared__ __align__(16) bf16 Wl[64][64];    // decayed W (separate: no W-epi barrier)
    __shared__ __align__(16) bf16 XTt[256][64];
    __shared__ float cumL[64], cumS[64];

    const int t = threadIdx.x, lane = t & 63, w = t >> 6;
    const int bid0 = blockIdx.x;
    const int bid = (bid0 & 7) * 256 + (bid0 >> 3);   // XCD swizzle, grid=2048
    const int zt = bid >> 2, lt = bid & 3;
    const int h = zt & 7, c = (zt >> 3) & 15, b = zt >> 7;
    const long blr = (long)b * LL + (long)c * CHK;
    const int bhc = (b * NH + h) * NC + c;
    const int l0 = lt * 64;
    const bf16* xrow = xdtT + ((long)b * DI + h * HD) * LL + c * CHK;

    // prefetch registers (T14 async-STAGE)
    uint4 xpre[8], bpre[2];
    float cpre = 0.f;
    auto LOADS = [&](int s0) {
#pragma unroll
        for (int i = 0; i < 8; i++) {
            int u = t + i * 256; int pp = u >> 3, pb = u & 7;
            xpre[i] = *(const uint4*)&xrow[(long)pp * LL + s0 + ((pb ^ (pp & 7)) << 3)];
        }
#pragma unroll
        for (int i = 0; i < 2; i++) {
            int u = t + i * 256; int row = u >> 3, pb = u & 7;
            bpre[i] = *(const uint4*)&bmat[(blr + s0 + row) * DS + ((pb ^ (row & 7)) << 3)];
        }
        if (t < 64) cpre = cumA[(long)bhc * CHK + s0 + t];
    };
    auto WRITES = [&]() {
#pragma unroll
        for (int i = 0; i < 8; i++) {
            int u = t + i * 256; int pp = u >> 3, pb = u & 7;
            *(uint4*)&XTt[pp][pb * 8] = xpre[i];
        }
#pragma unroll
        for (int i = 0; i < 2; i++) {
            int u = t + i * 256; int row = u >> 3, pb = u & 7;
            *(uint4*)&bW[row][pb * 8] = bpre[i];
        }
        if (t < 64) cumS[t] = cpre;
    };

    // stage c-tile (pre-swizzled source) + cumL; stage stile-0 data
#pragma unroll
    for (int i = 0; i < 2; i++) {
        int u = t + i * 256; int row = u >> 3, pb = u & 7;
        *(uint4*)&cT[row][pb * 8] =
            *(const uint4*)&cmat[(blr + l0 + row) * DS + ((pb ^ (row & 7)) << 3)];
    }
    if (t < 64) cumL[t] = cumA[(long)bhc * CHK + l0 + t];
    LOADS(0);
    WRITES();

    f4 acc[4][4];
#pragma unroll
    for (int mi = 0; mi < 4; mi++)
#pragma unroll
        for (int ni = 0; ni < 4; ni++) acc[mi][ni] = (f4){0.f, 0.f, 0.f, 0.f};
    __syncthreads();

    for (int stile = 0; stile <= lt; stile++) {
        // issue next stile's global loads (hide under W+Y compute)
        if (stile < lt) LOADS((stile + 1) * 64);

        // W-gemm: wave w -> W rows [w*16, w*16+16) x 64 s, K=64 (n)
        f4 wacc[4];
#pragma unroll
        for (int ni = 0; ni < 4; ni++) wacc[ni] = (f4){0.f, 0.f, 0.f, 0.f};
        __builtin_amdgcn_s_setprio(1);
#pragma unroll
        for (int ks = 0; ks < 2; ks++) {
            int kb = ks * 4 + (lane >> 4);
            int arow = w * 16 + (lane & 15);
            s8 af = *(const s8*)&cT[arow][(kb ^ (arow & 7)) << 3];
#pragma unroll
            for (int ni = 0; ni < 4; ni++) {
                int brow = ni * 16 + (lane & 15);
                s8 bfr = *(const s8*)&bW[brow][(kb ^ (brow & 7)) << 3];
                wacc[ni] = mfma16(af, bfr, wacc[ni]);
            }
        }
        __builtin_amdgcn_s_setprio(0);

        // epilogue: decay+mask -> bf16 into Wl (no barrier needed before: Wl != bW)
#pragma unroll
        for (int ni = 0; ni < 4; ni++) {
            int s_idx = ni * 16 + (lane & 15);
#pragma unroll
            for (int r = 0; r < 4; r++) {
                int l_loc = w * 16 + (lane >> 4) * 4 + r;
                bool valid = (stile < lt) || (l_loc >= s_idx);
                float val = valid ? wacc[ni][r] * __expf(cumL[l_loc] - cumS[s_idx]) : 0.f;
                Wl[l_loc][(((s_idx >> 3) ^ (l_loc & 7)) << 3) + (s_idx & 7)] =
                    __float2bfloat16(val);
            }
        }
        __syncthreads();   // Wl complete (and all bW reads done)

        // Y-gemm: wave w -> 64 l x p-range [w*64, w*64+64), K=64 (s)
        __builtin_amdgcn_s_setprio(1);
#pragma unroll
        for (int ks = 0; ks < 2; ks++) {
            int kb = ks * 4 + (lane >> 4);
            s8 aw[4], bx[4];
#pragma unroll
            for (int mi = 0; mi < 4; mi++) {
                int arow = mi * 16 + (lane & 15);
                aw[mi] = *(const s8*)&Wl[arow][(kb ^ (arow & 7)) << 3];
            }
#pragma unroll
            for (int ni = 0; ni < 4; ni++) {
                int p = w * 64 + ni * 16 + (lane & 15);
                bx[ni] = *(const s8*)&XTt[p][(kb ^ (p & 7)) << 3];
            }
#pragma unroll
            for (int mi = 0; mi < 4; mi++)
#pragma unroll
                for (int ni = 0; ni < 4; ni++)
                    acc[mi][ni] = mfma16(aw[mi], bx[ni], acc[mi][ni]);
        }
        __builtin_amdgcn_s_setprio(0);
        __syncthreads();   // XTt/bW reads done -> safe to overwrite

        if (stile < lt) {
            WRITES();
            __syncthreads();   // next stile's data visible
        }
    }

    // ---- inter-chunk state tile: Wl = cT*exp(cumL), XTt = st^T ----
#pragma unroll
    for (int i = 0; i < 16; i++) {
        int u = t + i * 256; int l = u >> 6, n = u & 63;
        int pc = (((n >> 3) ^ (l & 7)) << 3) + (n & 7);
        Wl[l][pc] = __float2bfloat16(__bfloat162float(cT[l][pc]) * __expf(cumL[l]));
    }
    {
        const bf16* sp = st + (long)zt * (HD * DS) + t * DS;
#pragma unroll
        for (int g = 0; g < 8; g++)
            *(uint4*)&XTt[t][g * 8] = *(const uint4*)&sp[(g ^ (t & 7)) << 3];
    }
    __syncthreads();
    __builtin_amdgcn_s_setprio(1);
#pragma unroll
    for (int ks = 0; ks < 2; ks++) {
        int kb = ks * 4 + (lane >> 4);
        s8 aw[4], bx[4];
#pragma unroll
        for (int mi = 0; mi < 4; mi++) {
            int arow = mi * 16 + (lane & 15);
            aw[mi] = *(const s8*)&Wl[arow][(kb ^ (arow & 7)) << 3];
        }
#pragma unroll
        for (int ni = 0; ni < 4; ni++) {
            int p = w * 64 + ni * 16 + (lane & 15);
            bx[ni] = *(const s8*)&XTt[p][(kb ^ (p & 7)) << 3];
        }
#pragma unroll
        for (int mi = 0; mi < 4; mi++)
#pragma unroll
            for (int ni = 0; ni < 4; ni++)
                acc[mi][ni] = mfma16(aw[mi], bx[ni], acc[mi][ni]);
    }
    __builtin_amdgcn_s_setprio(0);
    __syncthreads();

    // ---- epilogue: frags -> LDS -> coalesced global ----
    bf16* Yl = (bf16*)XTt;   // [64][256]
#pragma unroll
    for (int mi = 0; mi < 4; mi++)
#pragma unroll
        for (int ni = 0; ni < 4; ni++)
#pragma unroll
            for (int r = 0; r < 4; r++)
                Yl[(mi * 16 + (lane >> 4) * 4 + r) * 256 + w * 64 + ni * 16 + (lane & 15)] =
                    __float2bfloat16(acc[mi][ni][r]);
    __syncthreads();
#pragma unroll
    for (int i = 0; i < 8; i++) {
        int u = t + i * 256; int l = u >> 5, p8 = u & 31;
        *(uint4*)&y[(blr + l0 + l) * (long)ldy + h * HD + p8 * 8] =
            *(uint4*)&Yl[l * 256 + p8 * 8];
    }
}

// ---------------- gate (silu(z)) + RMSNorm, strided over zxbc ----------------
__global__ void gatenorm_kernel(const bf16* __restrict__ zxbc,
                                const float* __restrict__ gamma, bf16* __restrict__ out) {
    int row = blockIdx.x;
    int tid = threadIdx.x;
    int d0 = tid * 8;
    bf16 yv[8], zv[8];
    *(uint4*)yv = *(const uint4*)&zxbc[(long)row * ZXW + DI + d0];  // y (over xbc cols)
    *(uint4*)zv = *(const uint4*)&zxbc[(long)row * ZXW + d0];       // z
    float g[8];
    float ss = 0.f;
#pragma unroll
    for (int i = 0; i < 8; i++) {
        float zf = __bfloat162float(zv[i]);
        float gate = zf / (1.f + __expf(-zf));
        float v = __bfloat162float(yv[i]) * gate;
        g[i] = v;
        ss += v * v;
    }
#pragma unroll
    for (int off = 32; off > 0; off >>= 1) ss += __shfl_down(ss, off);
    __shared__ float red[4];
    if ((tid & 63) == 0) red[tid >> 6] = ss;
    __syncthreads();
    float tot = red[0] + red[1] + red[2] + red[3];
    float scale = rsqrtf(tot / (float)DI + 1e-5f);
    float4 g0 = *(const float4*)&gamma[d0];
    float4 g1 = *(const float4*)&gamma[d0 + 4];
    bf16 o[8];
    o[0] = __float2bfloat16(g[0] * scale * g0.x);
    o[1] = __float2bfloat16(g[1] * scale * g0.y);
    o[2] = __float2bfloat16(g[2] * scale * g0.z);
    o[3] = __float2bfloat16(g[3] * scale * g0.w);
    o[4] = __float2bfloat16(g[4] * scale * g1.x);
    o[5] = __float2bfloat16(g[5] * scale * g1.y);
    o[6] = __float2bfloat16(g[6] * scale * g1.z);
    o[7] = __float2bfloat16(g[7] * scale * g1.w);
    *(uint4*)&out[(long)row * ZXW + DI + d0] = *(uint4*)o;  // ynorm in place
}

extern "C" void kernel_launch(void* const* d_in, const int* in_sizes, int n_in,
                              void* d_out, int out_size, void* d_ws, size_t ws_size,
                              hipStream_t stream) {
    const float* inputs = (const float*)d_in[0];
    const float* Wz = (const float*)d_in[1];
    const float* Wxbc = (const float*)d_in[2];
    const float* Wdt = (const float*)d_in[3];
    const float* conv_kernel = (const float*)d_in[4];
    const float* dt_bias = (const float*)d_in[5];
    const float* a_log = (const float*)d_in[6];
    const float* gamma = (const float*)d_in[7];
    const float* Wout = (const float*)d_in[8];
    float* out = (float*)d_out;

    // ---- workspace layout (~223 MiB) ----
    char* p = (char*)d_ws;
    float* dtb = (float*)p;      p += (long)MROWS * NH * 4;
    float* cumA = (float*)p;     p += (long)MROWS * NH * 4;
    float* csum = (float*)p;     p += 512 * 4;
    bf16* WzT = (bf16*)p;        p += (long)DI * DM * 2;      // [WzT;WxbcT] adjacent
    bf16* WxbcT = (bf16*)p;      p += (long)CONVD * DM * 2;   //  = [4224][512]
    bf16* WoutT = (bf16*)p;      p += (long)DM * DI * 2;
    bf16* bmat = (bf16*)p;       p += (long)MROWS * DS * 2;
    bf16* cmat = (bf16*)p;       p += (long)MROWS * DS * 2;
    bf16* inA = (bf16*)p;        p += (long)MROWS * DM * 2;   // -> st (bf16) after GEMM
    bf16* zxbc = (bf16*)p;       p += (long)MROWS * ZXW * 2;  // z|xbc -> z|y -> z|ynorm
    bf16* xdtT = (bf16*)p;       p += (long)DI * BB * LL * 2; // 67 MB
    bf16* st = inA;

    // 1. casts / weight transposes
    cast_bf16_kernel<<<MROWS * DM / 8 / 256, 256, 0, stream>>>(inputs, inA);
    tcast_kernel<<<dim3(DI / 64, DM / 64), 256, 0, stream>>>(Wz, WzT, DM, DI);
    tcast_kernel<<<dim3(CONVD / 64, DM / 64), 256, 0, stream>>>(Wxbc, WxbcT, DM, CONVD);
    tcast_kernel<<<dim3(DM / 64, DI / 64), 256, 0, stream>>>(Wout, WoutT, DI, DM);
    // 2. zxbc = inA @ [Wz | Wxbc]   (single-buffer 128^2; grid = 128 mt * 33 nt)
    gemm_sb<bf16><<<128 * (ZXW / 128), 256, 0, stream>>>(
        inA, WzT, zxbc, ZXW, DM, DM, ZXW);
    // 3. dt
    dt_kernel<<<MROWS * NH / 256, 256, 0, stream>>>(inputs, Wdt, dt_bias, dtb);
    // 4. conv x-part -> xdtT (transposed);  b/c part -> bmat/cmat
    conv_x<<<BB * 64 * 32, 256, 0, stream>>>(zxbc, conv_kernel, dtb, xdtT);
    conv_bc<<<MROWS * 128 / 8 / 256, 256, 0, stream>>>(zxbc, conv_kernel, bmat, cmat);
    // 5. cumsum
    cumsum_kernel<<<2, 256, 0, stream>>>(dtb, a_log, cumA, csum);
    // 6. per-chunk states (MFMA) -> st (bf16, over dead inA)
    states_mfma<<<BB * NC * NH, 256, 0, stream>>>(bmat, xdtT, cumA, csum, st);
    // 7. chunk scan (in place)
    scan_kernel<<<BB * NH * HD * DS / 256, 256, 0, stream>>>(st, csum);
    // 8. fused SSD y (MFMA v3) -> y cols of zxbc (xbc dead after conv)
    ssd_y_mfma<<<BB * NC * NH * 4, 256, 0, stream>>>(
        bmat, cmat, xdtT, st, cumA, zxbc + DI, ZXW);
    // 9. gate + rmsnorm (ynorm in place over y)
    gatenorm_kernel<<<MROWS, 256, 0, stream>>>(zxbc, gamma, zxbc);
    // 10. out = ynorm @ Wout   (dbuf pipeline, K=2048; 1D grid = 128 mt * 4 nt)
    gemm_db<float><<<128 * (DM / 128), 256, 0, stream>>>(
        zxbc + DI, WoutT, out, DM, DI, ZXW, DM);
}

// Round 13
// 366.619 us; speedup vs baseline: 1.1433x; 1.1433x over previous
//
#include <hip/hip_runtime.h>
#include <hip/hip_bf16.h>

// Mamba2 block forward. B=4 L=4096 D_MODEL=512 D_INNER=2048 H=8 P=256 N=64
// CHUNK=256 C=16 CONV_DIM=2176.
// Round 13: revert ssd_y to r11 (r12's reg-prefetch spilled: WRITE 67->177MB,
// 124us). Keep r11 elsewhere. One safe add: gemm_db f32 LDS-staged epilogue
// (Wout writes were scalar 4B stores; now 16B coalesced).

#define BB 4
#define LL 4096
#define DM 512
#define DI 2048
#define NH 8
#define HD 256
#define DS 64
#define DCONV 4
#define CHK 256
#define NC 16
#define CONVD 2176
#define MROWS (BB*LL)    // 16384
#define ZXW (DI + CONVD) // 4224

typedef __hip_bfloat16 bf16;
typedef short s8 __attribute__((ext_vector_type(8)));   // 8 bf16 (4 VGPRs)
typedef float f4 __attribute__((ext_vector_type(4)));   // MFMA acc

__device__ __forceinline__ f4 mfma16(s8 a, s8 b, f4 c) {
    return __builtin_amdgcn_mfma_f32_16x16x32_bf16(a, b, c, 0, 0, 0);
}

__device__ __forceinline__ void gload16(const bf16* g, bf16* l) {
    __builtin_amdgcn_global_load_lds(
        (const __attribute__((address_space(1))) void*)g,
        (__attribute__((address_space(3))) void*)l, 16, 0, 0);
}

__device__ __forceinline__ float ldf(const float* p) { return *p; }
__device__ __forceinline__ float ldf(const bf16* p) { return __bfloat162float(*p); }
__device__ __forceinline__ void stf(float* p, float v) { *p = v; }
__device__ __forceinline__ void stf(bf16* p, float v) { *p = __float2bfloat16(v); }

// ---------------- f32 -> bf16 cast (8/thread) ----------------
__global__ void cast_bf16_kernel(const float* __restrict__ in, bf16* __restrict__ out) {
    long i8 = ((long)blockIdx.x * 256 + threadIdx.x) * 8;
    float4 a = *(const float4*)&in[i8];
    float4 b = *(const float4*)&in[i8 + 4];
    bf16 v[8];
    v[0] = __float2bfloat16(a.x); v[1] = __float2bfloat16(a.y);
    v[2] = __float2bfloat16(a.z); v[3] = __float2bfloat16(a.w);
    v[4] = __float2bfloat16(b.x); v[5] = __float2bfloat16(b.y);
    v[6] = __float2bfloat16(b.z); v[7] = __float2bfloat16(b.w);
    *(uint4*)&out[i8] = *(uint4*)v;
}

// ---------------- f32 [K][N] -> bf16 [N][K] transpose-cast (weights) ----------------
__global__ void tcast_kernel(const float* __restrict__ in, bf16* __restrict__ out,
                             int K, int N) {
    __shared__ float tile[64][65];
    int t = threadIdx.x;
    int n0 = blockIdx.x * 64, k0 = blockIdx.y * 64;
#pragma unroll
    for (int i = 0; i < 16; i++) {
        int u = t + i * 256; int kr = u >> 6, nc = u & 63;
        tile[kr][nc] = in[(long)(k0 + kr) * N + n0 + nc];
    }
    __syncthreads();
#pragma unroll
    for (int i = 0; i < 16; i++) {
        int u = t + i * 256; int nr = u >> 6, kc = u & 63;
        out[(long)(n0 + nr) * K + k0 + kc] = __float2bfloat16(tile[kc][nr]);
    }
}

// ---------------- gemm_sb: single-buffered 128^2, 4 blocks/CU ----------------
template <typename TC>
__global__ __launch_bounds__(256, 4) void gemm_sb(const bf16* __restrict__ A,
                                                  const bf16* __restrict__ BT,
                                                  TC* __restrict__ C, int N, int K,
                                                  int lda, int ldc) {
    __shared__ __align__(16) char smem[34816];  // staging 32KB | bf16 C-epilogue 34KB
    bf16 (*At)[64] = (bf16(*)[64])smem;
    bf16 (*Bt)[64] = (bf16(*)[64])(smem + 16384);
    const int t = threadIdx.x, lane = t & 63, w = t >> 6;
    const int wr = w >> 1, wc = w & 1;
    const int bid = blockIdx.x;
    const int idx = bid >> 3;
    const int mt = (bid & 7) * 16 + (idx & 15);   // nMt = 128 fixed
    const int nt = idx >> 4;
    const long m0 = (long)mt * 128;
    const int n0 = nt * 128;
    const int lrow = lane >> 3, lblk = lane & 7;
    f4 acc[4][4];
#pragma unroll
    for (int mi = 0; mi < 4; mi++)
#pragma unroll
        for (int ni = 0; ni < 4; ni++) acc[mi][ni] = (f4){0.f, 0.f, 0.f, 0.f};

    for (int k0 = 0; k0 < K; k0 += 64) {
#pragma unroll
        for (int i = 0; i < 4; i++) {
            int rbase = w * 32 + i * 8;
            int row = rbase + lrow;
            int kb = (lblk ^ (row & 7)) << 3;   // source k-block, pre-swizzled
            gload16(&A[(m0 + row) * (long)lda + k0 + kb], &At[rbase][0]);
            gload16(&BT[((long)n0 + row) * K + k0 + kb], &Bt[rbase][0]);
        }
        __syncthreads();
        __builtin_amdgcn_s_setprio(1);
#pragma unroll
        for (int ks = 0; ks < 2; ks++) {
            int k8 = ks * 4 + (lane >> 4);
            s8 af[4], bfr[4];
#pragma unroll
            for (int mi = 0; mi < 4; mi++) {
                int row = wr * 64 + mi * 16 + (lane & 15);
                af[mi] = *(const s8*)&At[row][(k8 ^ (row & 7)) << 3];
            }
#pragma unroll
            for (int ni = 0; ni < 4; ni++) {
                int row = wc * 64 + ni * 16 + (lane & 15);
                bfr[ni] = *(const s8*)&Bt[row][(k8 ^ (row & 7)) << 3];
            }
#pragma unroll
            for (int mi = 0; mi < 4; mi++)
#pragma unroll
                for (int ni = 0; ni < 4; ni++)
                    acc[mi][ni] = mfma16(af[mi], bfr[ni], acc[mi][ni]);
        }
        __builtin_amdgcn_s_setprio(0);
        __syncthreads();
    }
    if constexpr (sizeof(TC) == 2) {
        bf16 (*Ct)[136] = (bf16(*)[136])smem;
#pragma unroll
        for (int mi = 0; mi < 4; mi++)
#pragma unroll
            for (int ni = 0; ni < 4; ni++)
#pragma unroll
                for (int r = 0; r < 4; r++)
                    Ct[wr * 64 + mi * 16 + (lane >> 4) * 4 + r]
                      [wc * 64 + ni * 16 + (lane & 15)] =
                        __float2bfloat16(acc[mi][ni][r]);
        __syncthreads();
#pragma unroll
        for (int i = 0; i < 8; i++) {
            int u = t + i * 256; int row = u >> 4, j = u & 15;
            *(uint4*)&C[(m0 + row) * (long)ldc + n0 + j * 8] = *(uint4*)&Ct[row][j * 8];
        }
    } else {
#pragma unroll
        for (int mi = 0; mi < 4; mi++)
#pragma unroll
            for (int ni = 0; ni < 4; ni++)
#pragma unroll
                for (int r = 0; r < 4; r++)
                    stf(&C[(m0 + wr * 64 + mi * 16 + (lane >> 4) * 4 + r) * (long)ldc +
                           n0 + wc * 64 + ni * 16 + (lane & 15)], acc[mi][ni][r]);
    }
}

// ---------------- gemm_db: 2-phase dbuf 128^2 — used for Wout (K=2048) ----------------
template <typename TC>
__global__ __launch_bounds__(256) void gemm_db(const bf16* __restrict__ A,
                                               const bf16* __restrict__ BT,
                                               TC* __restrict__ C, int N, int K,
                                               int lda, int ldc) {
    __shared__ __align__(16) char smem[65536];
    bf16 (*At)[128][64] = (bf16(*)[128][64])smem;
    bf16 (*Bt)[128][64] = (bf16(*)[128][64])(smem + 32768);
    const int t = threadIdx.x, lane = t & 63, w = t >> 6;
    const int wr = w >> 1, wc = w & 1;
    const int bid = blockIdx.x;
    const int idx = bid >> 3;
    const int nNt = N >> 7;
    const int nt = idx % nNt;                       // nt fastest
    const int mt = (bid & 7) * 16 + (idx / nNt);    // nMt = 128 fixed
    const long m0 = (long)mt * 128;
    const int n0 = nt * 128;
    const int lrow = lane >> 3, lblk = lane & 7;
    const int KT = K >> 6;
    f4 acc[4][4];
#pragma unroll
    for (int mi = 0; mi < 4; mi++)
#pragma unroll
        for (int ni = 0; ni < 4; ni++) acc[mi][ni] = (f4){0.f, 0.f, 0.f, 0.f};

    auto STAGE = [&](int bu, int kt) {
        int k0 = kt << 6;
#pragma unroll
        for (int i = 0; i < 4; i++) {
            int rbase = w * 32 + i * 8;
            int row = rbase + lrow;
            int kb = (lblk ^ (row & 7)) << 3;
            gload16(&A[(m0 + row) * (long)lda + k0 + kb], &At[bu][rbase][0]);
            gload16(&BT[((long)n0 + row) * K + k0 + kb], &Bt[bu][rbase][0]);
        }
    };

    STAGE(0, 0);
    int bu = 0;
    for (int kt = 0; kt < KT; kt++) {
        if (kt + 1 < KT) {
            STAGE(bu ^ 1, kt + 1);
            asm volatile("s_waitcnt vmcnt(8)" ::: "memory");
        } else {
            asm volatile("s_waitcnt vmcnt(0)" ::: "memory");
        }
        __builtin_amdgcn_sched_barrier(0);
        __builtin_amdgcn_s_barrier();
        __builtin_amdgcn_s_setprio(1);
#pragma unroll
        for (int ks = 0; ks < 2; ks++) {
            int k8 = ks * 4 + (lane >> 4);
            s8 af[4], bfr[4];
#pragma unroll
            for (int mi = 0; mi < 4; mi++) {
                int row = wr * 64 + mi * 16 + (lane & 15);
                af[mi] = *(const s8*)&At[bu][row][(k8 ^ (row & 7)) << 3];
            }
#pragma unroll
            for (int ni = 0; ni < 4; ni++) {
                int row = wc * 64 + ni * 16 + (lane & 15);
                bfr[ni] = *(const s8*)&Bt[bu][row][(k8 ^ (row & 7)) << 3];
            }
#pragma unroll
            for (int mi = 0; mi < 4; mi++)
#pragma unroll
                for (int ni = 0; ni < 4; ni++)
                    acc[mi][ni] = mfma16(af[mi], bfr[ni], acc[mi][ni]);
        }
        __builtin_amdgcn_s_setprio(0);
        __builtin_amdgcn_s_barrier();
        bu ^= 1;
    }
    __syncthreads();
    if constexpr (sizeof(TC) == 2) {
        bf16 (*Ct)[136] = (bf16(*)[136])smem;
#pragma unroll
        for (int mi = 0; mi < 4; mi++)
#pragma unroll
            for (int ni = 0; ni < 4; ni++)
#pragma unroll
                for (int r = 0; r < 4; r++)
                    Ct[wr * 64 + mi * 16 + (lane >> 4) * 4 + r]
                      [wc * 64 + ni * 16 + (lane & 15)] =
                        __float2bfloat16(acc[mi][ni][r]);
        __syncthreads();
#pragma unroll
        for (int i = 0; i < 8; i++) {
            int u = t + i * 256; int row = u >> 4, j = u & 15;
            *(uint4*)&C[(m0 + row) * (long)ldc + n0 + j * 8] = *(uint4*)&Ct[row][j * 8];
        }
    } else {
        // f32 LDS-staged epilogue: two 64-row passes, 16B coalesced stores
        float (*Ctf)[132] = (float(*)[132])smem;   // 64*132*4 = 33.8KB
#pragma unroll
        for (int pass = 0; pass < 2; pass++) {
            if (wr == pass) {
#pragma unroll
                for (int mi = 0; mi < 4; mi++)
#pragma unroll
                    for (int ni = 0; ni < 4; ni++)
#pragma unroll
                        for (int r = 0; r < 4; r++)
                            Ctf[mi * 16 + (lane >> 4) * 4 + r]
                               [wc * 64 + ni * 16 + (lane & 15)] = acc[mi][ni][r];
            }
            __syncthreads();
#pragma unroll
            for (int i = 0; i < 8; i++) {
                int u = t + i * 256; int row = u >> 5, q = u & 31;
                *(float4*)&C[(m0 + pass * 64 + row) * (long)ldc + n0 + q * 4] =
                    *(float4*)&Ctf[row][q * 4];
            }
            __syncthreads();
        }
    }
}

// ---------------- dt = softplus(inputs @ Wdt + bias) ----------------
__global__ void dt_kernel(const float* __restrict__ inp, const float* __restrict__ Wdt,
                          const float* __restrict__ dt_bias, float* __restrict__ dtb) {
    __shared__ float wlds[DM * NH];  // 16 KB
    int t = threadIdx.x;
#pragma unroll
    for (int i = 0; i < 16; i++) wlds[t + i * 256] = Wdt[t + i * 256];
    __syncthreads();
    int idx = blockIdx.x * 256 + t;
    int h = idx & 7;
    long row = idx >> 3;
    const float* ir = inp + row * DM;
    float acc = 0.f;
    for (int k = 0; k < DM; k += 4) {
        float4 a = *(const float4*)&ir[k];
        acc += a.x * wlds[k * 8 + h] + a.y * wlds[(k + 1) * 8 + h]
             + a.z * wlds[(k + 2) * 8 + h] + a.w * wlds[(k + 3) * 8 + h];
    }
    acc += dt_bias[h];
    float sp = acc > 20.f ? acc : log1pf(expf(acc));
    dtb[idx] = sp;
}

// ---------------- conv_x: conv(4)+silu+*dt over x channels, writes xdtT ----------------
__global__ __launch_bounds__(256) void conv_x(const bf16* __restrict__ zxbc,
                                              const float* __restrict__ ck,
                                              const float* __restrict__ dtb,
                                              bf16* __restrict__ xdtT) {
    __shared__ __align__(16) bf16 in_lds[67][72];
    __shared__ __align__(16) bf16 out_lds[64][64];
    __shared__ float dts[64];
    const int bid = blockIdx.x;
    const int ct = bid & 31, lt = (bid >> 5) & 63, b = bid >> 11;
    const int t = threadIdx.x;
    const int l0 = lt * 64;
    const long brow = (long)b * LL;
    const int h = ct >> 2;

#pragma unroll
    for (int i = 0; i < 3; i++) {
        int u = t + i * 256;
        if (u < 536) {
            int r = u >> 3, c8 = (u & 7) * 8;
            int gl = l0 - 3 + r;
            uint4 v = (gl >= 0)
                ? *(const uint4*)&zxbc[(brow + gl) * ZXW + DI + ct * 64 + c8]
                : (uint4){0, 0, 0, 0};
            *(uint4*)&in_lds[r][c8] = v;
        }
    }
    if (t < 64) dts[t] = dtb[(brow + l0 + t) * NH + h];
    __syncthreads();

    const int ch = t & 63, w = t >> 6;
    const int gch = ct * 64 + ch;
    float k0 = ck[0 * CONVD + gch], k1 = ck[1 * CONVD + gch];
    float k2 = ck[2 * CONVD + gch], k3 = ck[3 * CONVD + gch];
    float w0 = __bfloat162float(in_lds[w * 16 + 0][ch]);
    float w1 = __bfloat162float(in_lds[w * 16 + 1][ch]);
    float w2 = __bfloat162float(in_lds[w * 16 + 2][ch]);
    bf16 o[16];
#pragma unroll
    for (int i = 0; i < 16; i++) {
        float w3 = __bfloat162float(in_lds[w * 16 + i + 3][ch]);
        float v = w0 * k0 + w1 * k1 + w2 * k2 + w3 * k3;
        float s = v / (1.f + __expf(-v));
        o[i] = __float2bfloat16(s * dts[w * 16 + i]);
        w0 = w1; w1 = w2; w2 = w3;
    }
#pragma unroll
    for (int j = 0; j < 2; j++) {
        int blk = w * 2 + j;
        *(uint4*)&out_lds[ch][((blk ^ (ch & 7)) << 3)] = *(uint4*)&o[j * 8];
    }
    __syncthreads();
#pragma unroll
    for (int i = 0; i < 2; i++) {
        int u = t + i * 256;
        int chr = u >> 3, l8 = u & 7;
        uint4 v = *(const uint4*)&out_lds[chr][((l8 ^ (chr & 7)) << 3)];
        *(uint4*)&xdtT[((long)b * DI + ct * 64 + chr) * LL + l0 + l8 * 8] = v;
    }
}

// ---------------- conv_bc: conv+silu for b/c channels ----------------
__global__ void conv_bc(const bf16* __restrict__ zxbc, const float* __restrict__ ck,
                        bf16* __restrict__ bm, bf16* __restrict__ cm) {
    long idx = (long)blockIdx.x * 256 + threadIdx.x;
    if (idx >= (long)MROWS * 128 / 8) return;
    long e0 = idx * 8;
    int ch = (int)(e0 & 127);
    long bl = e0 >> 7;
    int l = (int)(bl & (LL - 1));
    float acc[8] = {};
#pragma unroll
    for (int k = 0; k < DCONV; k++) {
        int ls = l - 3 + k;
        if (ls >= 0) {
            bf16 v[8];
            *(uint4*)v = *(const uint4*)&zxbc[(bl - l + ls) * ZXW + 2 * DI + ch];
            float4 c0 = *(const float4*)&ck[k * CONVD + DI + ch];
            float4 c1 = *(const float4*)&ck[k * CONVD + DI + ch + 4];
            acc[0] += __bfloat162float(v[0]) * c0.x;
            acc[1] += __bfloat162float(v[1]) * c0.y;
            acc[2] += __bfloat162float(v[2]) * c0.z;
            acc[3] += __bfloat162float(v[3]) * c0.w;
            acc[4] += __bfloat162float(v[4]) * c1.x;
            acc[5] += __bfloat162float(v[5]) * c1.y;
            acc[6] += __bfloat162float(v[6]) * c1.z;
            acc[7] += __bfloat162float(v[7]) * c1.w;
        }
    }
    bf16 o[8];
#pragma unroll
    for (int j = 0; j < 8; j++) {
        float s = acc[j] / (1.f + __expf(-acc[j]));
        o[j] = __float2bfloat16(s);
    }
    if (ch < DS) *(uint4*)&bm[bl * DS + ch] = *(uint4*)o;
    else         *(uint4*)&cm[bl * DS + (ch - DS)] = *(uint4*)o;
}

// ---------------- per-(b,h,c) cumsum of a*dt ----------------
__global__ void cumsum_kernel(const float* __restrict__ dtb, const float* __restrict__ a_log,
                              float* __restrict__ cumA, float* __restrict__ csum) {
    int t = blockIdx.x * 256 + threadIdx.x;  // t = b*128 + h*16 + c
    if (t >= BB * NH * NC) return;
    int c = t & 15, h = (t >> 4) & 7, b = t >> 7;
    float a = -expf(a_log[h]);
    long base_l = (long)b * LL + (long)c * CHK;
    float s = 0.f;
    long obase = (long)t * CHK;
    for (int i = 0; i < CHK; i++) {
        s += a * dtb[(base_l + i) * NH + h];
        cumA[obase + i] = s;
    }
    csum[t] = s;
}

// ---------------- states via MFMA: st[p][n] = sum_l x[l,p]*b[l,n]*dec[l] ----------------
__global__ __launch_bounds__(256, 4) void states_mfma(
        const bf16* __restrict__ bmat, const bf16* __restrict__ xdtT,
        const float* __restrict__ cumA, const float* __restrict__ csum,
        bf16* __restrict__ st) {
    __shared__ __align__(16) bf16 XT[256][72];
    __shared__ __align__(16) bf16 BT[64][72];
    const int z = blockIdx.x;  // b*128 + c*8 + h
    const int h = z & 7, c = (z >> 3) & 15, b = z >> 7;
    const long blr = (long)b * LL + (long)c * CHK;
    const int bhc = (b * NH + h) * NC + c;
    const float A = csum[bhc];
    const int t = threadIdx.x, lane = t & 63, w = t >> 6;
    const bf16* xrow = xdtT + ((long)b * DI + h * HD) * LL + c * CHK;
    f4 acc[4][4];
#pragma unroll
    for (int mi = 0; mi < 4; mi++)
#pragma unroll
        for (int ni = 0; ni < 4; ni++) acc[mi][ni] = (f4){0.f, 0.f, 0.f, 0.f};

    for (int lt = 0; lt < 4; lt++) {
        const int l0 = lt * 64;
#pragma unroll
        for (int i = 0; i < 2; i++) {
            int u = t + i * 256; int l = u >> 3, n8 = (u & 7) * 8;
            bf16 v[8];
            *(uint4*)v = *(const uint4*)&bmat[(blr + l0 + l) * DS + n8];
            float d = __expf(A - cumA[(long)bhc * CHK + l0 + l]);
#pragma unroll
            for (int j = 0; j < 8; j++) {
                int n = n8 + j;
                BT[n][l ^ ((n & 7) << 3)] = __float2bfloat16(__bfloat162float(v[j]) * d);
            }
        }
#pragma unroll
        for (int i = 0; i < 8; i++) {
            int u = t + i * 256; int pp = u >> 3, s8v = u & 7;
            *(uint4*)&XT[pp][s8v * 8] =
                *(const uint4*)&xrow[(long)pp * LL + l0 + ((s8v ^ (pp & 7)) << 3)];
        }
        __syncthreads();
        __builtin_amdgcn_s_setprio(1);
#pragma unroll
        for (int ks = 0; ks < 2; ks++) {
            int col = ks * 32 + (lane >> 4) * 8;
            s8 af[4], bx[4];
#pragma unroll
            for (int mi = 0; mi < 4; mi++) {
                int n = mi * 16 + (lane & 15);
                af[mi] = *(const s8*)&BT[n][col ^ ((n & 7) << 3)];
            }
#pragma unroll
            for (int ni = 0; ni < 4; ni++) {
                int p = w * 64 + ni * 16 + (lane & 15);
                bx[ni] = *(const s8*)&XT[p][col ^ ((p & 7) << 3)];
            }
#pragma unroll
            for (int mi = 0; mi < 4; mi++)
#pragma unroll
                for (int ni = 0; ni < 4; ni++)
                    acc[mi][ni] = mfma16(af[mi], bx[ni], acc[mi][ni]);
        }
        __builtin_amdgcn_s_setprio(0);
        __syncthreads();
    }
    bf16* so = st + (long)z * (HD * DS);
#pragma unroll
    for (int mi = 0; mi < 4; mi++)
#pragma unroll
        for (int ni = 0; ni < 4; ni++) {
            int p = w * 64 + ni * 16 + (lane & 15);
            int n0 = mi * 16 + (lane >> 4) * 4;
            bf16 vv[4];
#pragma unroll
            for (int r = 0; r < 4; r++) vv[r] = __float2bfloat16(acc[mi][ni][r]);
            *(uint2*)&so[p * 64 + n0] = *(uint2*)vv;
        }
}

// ---------------- serial chunk scan (in place, bf16, f32 accum in regs) ----------------
__global__ void scan_kernel(bf16* __restrict__ st, const float* __restrict__ csum) {
    long idx = (long)blockIdx.x * 256 + threadIdx.x;
    int pn = (int)(idx & 16383);
    int h = (int)((idx >> 14) & 7);
    int b = (int)(idx >> 17);
    float S = 0.f;
    for (int c = 0; c < NC; c++) {
        long si = (((long)(b * NC + c) * NH + h) * (HD * DS)) + pn;
        float chunk = __bfloat162float(st[si]);
        st[si] = __float2bfloat16(S);
        S = S * __expf(csum[(b * NH + h) * NC + c]) + chunk;
    }
}

// ---------------- fused SSD y via MFMA (r11 version, uniform XOR-swizzle) ----------------
__global__ __launch_bounds__(256, 3) void ssd_y_mfma(
        const bf16* __restrict__ bmat, const bf16* __restrict__ cmat,
        const bf16* __restrict__ xdtT, const bf16* __restrict__ st,
        const float* __restrict__ cumA, bf16* __restrict__ y, int ldy) {
    __shared__ __align__(16) bf16 cT[64][64];
    __shared__ __align__(16) bf16 bW[64][64];
    __shared__ __align__(16) bf16 XTt[256][64];
    __shared__ float cumL[64], cumS[64];

    const int t = threadIdx.x, lane = t & 63, w = t >> 6;
    const int bid0 = blockIdx.x;
    const int bid = (bid0 & 7) * 256 + (bid0 >> 3);   // XCD swizzle, grid=2048
    const int zt = bid >> 2, lt = bid & 3;
    const int h = zt & 7, c = (zt >> 3) & 15, b = zt >> 7;
    const long blr = (long)b * LL + (long)c * CHK;
    const int bhc = (b * NH + h) * NC + c;
    const int l0 = lt * 64;
    const bf16* xrow = xdtT + ((long)b * DI + h * HD) * LL + c * CHK;

#pragma unroll
    for (int i = 0; i < 2; i++) {
        int u = t + i * 256; int row = u >> 3, pb = u & 7;
        *(uint4*)&cT[row][pb * 8] =
            *(const uint4*)&cmat[(blr + l0 + row) * DS + ((pb ^ (row & 7)) << 3)];
    }
    if (t < 64) cumL[t] = cumA[(long)bhc * CHK + l0 + t];

    f4 acc[4][4];
#pragma unroll
    for (int mi = 0; mi < 4; mi++)
#pragma unroll
        for (int ni = 0; ni < 4; ni++) acc[mi][ni] = (f4){0.f, 0.f, 0.f, 0.f};
    __syncthreads();

    for (int stile = 0; stile <= lt; stile++) {
        const int s0 = stile * 64;
#pragma unroll
        for (int i = 0; i < 2; i++) {
            int u = t + i * 256; int row = u >> 3, pb = u & 7;
            *(uint4*)&bW[row][pb * 8] =
                *(const uint4*)&bmat[(blr + s0 + row) * DS + ((pb ^ (row & 7)) << 3)];
        }
        if (t < 64) cumS[t] = cumA[(long)bhc * CHK + s0 + t];
#pragma unroll
        for (int i = 0; i < 8; i++) {
            int u = t + i * 256; int pp = u >> 3, pb = u & 7;
            *(uint4*)&XTt[pp][pb * 8] =
                *(const uint4*)&xrow[(long)pp * LL + s0 + ((pb ^ (pp & 7)) << 3)];
        }
        __syncthreads();

        f4 wacc[4];
#pragma unroll
        for (int ni = 0; ni < 4; ni++) wacc[ni] = (f4){0.f, 0.f, 0.f, 0.f};
        __builtin_amdgcn_s_setprio(1);
#pragma unroll
        for (int ks = 0; ks < 2; ks++) {
            int kb = ks * 4 + (lane >> 4);
            int arow = w * 16 + (lane & 15);
            s8 af = *(const s8*)&cT[arow][(kb ^ (arow & 7)) << 3];
#pragma unroll
            for (int ni = 0; ni < 4; ni++) {
                int brow = ni * 16 + (lane & 15);
                s8 bfr = *(const s8*)&bW[brow][(kb ^ (brow & 7)) << 3];
                wacc[ni] = mfma16(af, bfr, wacc[ni]);
            }
        }
        __builtin_amdgcn_s_setprio(0);
        __syncthreads();

#pragma unroll
        for (int ni = 0; ni < 4; ni++) {
            int s_idx = ni * 16 + (lane & 15);
#pragma unroll
            for (int r = 0; r < 4; r++) {
                int l_loc = w * 16 + (lane >> 4) * 4 + r;
                bool valid = (stile < lt) || (l_loc >= s_idx);
                float val = valid ? wacc[ni][r] * __expf(cumL[l_loc] - cumS[s_idx]) : 0.f;
                bW[l_loc][(((s_idx >> 3) ^ (l_loc & 7)) << 3) + (s_idx & 7)] =
                    __float2bfloat16(val);
            }
        }
        __syncthreads();

        __builtin_amdgcn_s_setprio(1);
#pragma unroll
        for (int ks = 0; ks < 2; ks++) {
            int kb = ks * 4 + (lane >> 4);
            s8 aw[4], bx[4];
#pragma unroll
            for (int mi = 0; mi < 4; mi++) {
                int arow = mi * 16 + (lane & 15);
                aw[mi] = *(const s8*)&bW[arow][(kb ^ (arow & 7)) << 3];
            }
#pragma unroll
            for (int ni = 0; ni < 4; ni++) {
                int p = w * 64 + ni * 16 + (lane & 15);
                bx[ni] = *(const s8*)&XTt[p][(kb ^ (p & 7)) << 3];
            }
#pragma unroll
            for (int mi = 0; mi < 4; mi++)
#pragma unroll
                for (int ni = 0; ni < 4; ni++)
                    acc[mi][ni] = mfma16(aw[mi], bx[ni], acc[mi][ni]);
        }
        __builtin_amdgcn_s_setprio(0);
        __syncthreads();
    }

#pragma unroll
    for (int i = 0; i < 16; i++) {
        int u = t + i * 256; int l = u >> 6, n = u & 63;
        int pc = (((n >> 3) ^ (l & 7)) << 3) + (n & 7);
        bW[l][pc] = __float2bfloat16(__bfloat162float(cT[l][pc]) * __expf(cumL[l]));
    }
    {
        const bf16* sp = st + (long)zt * (HD * DS) + t * DS;
#pragma unroll
        for (int g = 0; g < 8; g++)
            *(uint4*)&XTt[t][g * 8] = *(const uint4*)&sp[(g ^ (t & 7)) << 3];
    }
    __syncthreads();
    __builtin_amdgcn_s_setprio(1);
#pragma unroll
    for (int ks = 0; ks < 2; ks++) {
        int kb = ks * 4 + (lane >> 4);
        s8 aw[4], bx[4];
#pragma unroll
        for (int mi = 0; mi < 4; mi++) {
            int arow = mi * 16 + (lane & 15);
            aw[mi] = *(const s8*)&bW[arow][(kb ^ (arow & 7)) << 3];
        }
#pragma unroll
        for (int ni = 0; ni < 4; ni++) {
            int p = w * 64 + ni * 16 + (lane & 15);
            bx[ni] = *(const s8*)&XTt[p][(kb ^ (p & 7)) << 3];
        }
#pragma unroll
        for (int mi = 0; mi < 4; mi++)
#pragma unroll
            for (int ni = 0; ni < 4; ni++)
                acc[mi][ni] = mfma16(aw[mi], bx[ni], acc[mi][ni]);
    }
    __builtin_amdgcn_s_setprio(0);
    __syncthreads();

    bf16* Yl = (bf16*)XTt;   // [64][256]
#pragma unroll
    for (int mi = 0; mi < 4; mi++)
#pragma unroll
        for (int ni = 0; ni < 4; ni++)
#pragma unroll
            for (int r = 0; r < 4; r++)
                Yl[(mi * 16 + (lane >> 4) * 4 + r) * 256 + w * 64 + ni * 16 + (lane & 15)] =
                    __float2bfloat16(acc[mi][ni][r]);
    __syncthreads();
#pragma unroll
    for (int i = 0; i < 8; i++) {
        int u = t + i * 256; int l = u >> 5, p8 = u & 31;
        *(uint4*)&y[(blr + l0 + l) * (long)ldy + h * HD + p8 * 8] =
            *(uint4*)&Yl[l * 256 + p8 * 8];
    }
}

// ---------------- gate (silu(z)) + RMSNorm, strided over zxbc ----------------
__global__ void gatenorm_kernel(const bf16* __restrict__ zxbc,
                                const float* __restrict__ gamma, bf16* __restrict__ out) {
    int row = blockIdx.x;
    int tid = threadIdx.x;
    int d0 = tid * 8;
    bf16 yv[8], zv[8];
    *(uint4*)yv = *(const uint4*)&zxbc[(long)row * ZXW + DI + d0];  // y (over xbc cols)
    *(uint4*)zv = *(const uint4*)&zxbc[(long)row * ZXW + d0];       // z
    float g[8];
    float ss = 0.f;
#pragma unroll
    for (int i = 0; i < 8; i++) {
        float zf = __bfloat162float(zv[i]);
        float gate = zf / (1.f + __expf(-zf));
        float v = __bfloat162float(yv[i]) * gate;
        g[i] = v;
        ss += v * v;
    }
#pragma unroll
    for (int off = 32; off > 0; off >>= 1) ss += __shfl_down(ss, off);
    __shared__ float red[4];
    if ((tid & 63) == 0) red[tid >> 6] = ss;
    __syncthreads();
    float tot = red[0] + red[1] + red[2] + red[3];
    float scale = rsqrtf(tot / (float)DI + 1e-5f);
    float4 g0 = *(const float4*)&gamma[d0];
    float4 g1 = *(const float4*)&gamma[d0 + 4];
    bf16 o[8];
    o[0] = __float2bfloat16(g[0] * scale * g0.x);
    o[1] = __float2bfloat16(g[1] * scale * g0.y);
    o[2] = __float2bfloat16(g[2] * scale * g0.z);
    o[3] = __float2bfloat16(g[3] * scale * g0.w);
    o[4] = __float2bfloat16(g[4] * scale * g1.x);
    o[5] = __float2bfloat16(g[5] * scale * g1.y);
    o[6] = __float2bfloat16(g[6] * scale * g1.z);
    o[7] = __float2bfloat16(g[7] * scale * g1.w);
    *(uint4*)&out[(long)row * ZXW + DI + d0] = *(uint4*)o;  // ynorm in place
}

extern "C" void kernel_launch(void* const* d_in, const int* in_sizes, int n_in,
                              void* d_out, int out_size, void* d_ws, size_t ws_size,
                              hipStream_t stream) {
    const float* inputs = (const float*)d_in[0];
    const float* Wz = (const float*)d_in[1];
    const float* Wxbc = (const float*)d_in[2];
    const float* Wdt = (const float*)d_in[3];
    const float* conv_kernel = (const float*)d_in[4];
    const float* dt_bias = (const float*)d_in[5];
    const float* a_log = (const float*)d_in[6];
    const float* gamma = (const float*)d_in[7];
    const float* Wout = (const float*)d_in[8];
    float* out = (float*)d_out;

    // ---- workspace layout (~223 MiB) ----
    char* p = (char*)d_ws;
    float* dtb = (float*)p;      p += (long)MROWS * NH * 4;
    float* cumA = (float*)p;     p += (long)MROWS * NH * 4;
    float* csum = (float*)p;     p += 512 * 4;
    bf16* WzT = (bf16*)p;        p += (long)DI * DM * 2;      // [WzT;WxbcT] adjacent
    bf16* WxbcT = (bf16*)p;      p += (long)CONVD * DM * 2;   //  = [4224][512]
    bf16* WoutT = (bf16*)p;      p += (long)DM * DI * 2;
    bf16* bmat = (bf16*)p;       p += (long)MROWS * DS * 2;
    bf16* cmat = (bf16*)p;       p += (long)MROWS * DS * 2;
    bf16* inA = (bf16*)p;        p += (long)MROWS * DM * 2;   // -> st (bf16) after GEMM
    bf16* zxbc = (bf16*)p;       p += (long)MROWS * ZXW * 2;  // z|xbc -> z|y -> z|ynorm
    bf16* xdtT = (bf16*)p;       p += (long)DI * BB * LL * 2; // 67 MB
    bf16* st = inA;

    // 1. casts / weight transposes
    cast_bf16_kernel<<<MROWS * DM / 8 / 256, 256, 0, stream>>>(inputs, inA);
    tcast_kernel<<<dim3(DI / 64, DM / 64), 256, 0, stream>>>(Wz, WzT, DM, DI);
    tcast_kernel<<<dim3(CONVD / 64, DM / 64), 256, 0, stream>>>(Wxbc, WxbcT, DM, CONVD);
    tcast_kernel<<<dim3(DM / 64, DI / 64), 256, 0, stream>>>(Wout, WoutT, DI, DM);
    // 2. zxbc = inA @ [Wz | Wxbc]   (single-buffer 128^2; grid = 128 mt * 33 nt)
    gemm_sb<bf16><<<128 * (ZXW / 128), 256, 0, stream>>>(
        inA, WzT, zxbc, ZXW, DM, DM, ZXW);
    // 3. dt
    dt_kernel<<<MROWS * NH / 256, 256, 0, stream>>>(inputs, Wdt, dt_bias, dtb);
    // 4. conv x-part -> xdtT (transposed);  b/c part -> bmat/cmat
    conv_x<<<BB * 64 * 32, 256, 0, stream>>>(zxbc, conv_kernel, dtb, xdtT);
    conv_bc<<<MROWS * 128 / 8 / 256, 256, 0, stream>>>(zxbc, conv_kernel, bmat, cmat);
    // 5. cumsum
    cumsum_kernel<<<2, 256, 0, stream>>>(dtb, a_log, cumA, csum);
    // 6. per-chunk states (MFMA) -> st (bf16, over dead inA)
    states_mfma<<<BB * NC * NH, 256, 0, stream>>>(bmat, xdtT, cumA, csum, st);
    // 7. chunk scan (in place)
    scan_kernel<<<BB * NH * HD * DS / 256, 256, 0, stream>>>(st, csum);
    // 8. fused SSD y (MFMA) -> y cols of zxbc (xbc dead after conv)
    ssd_y_mfma<<<BB * NC * NH * 4, 256, 0, stream>>>(
        bmat, cmat, xdtT, st, cumA, zxbc + DI, ZXW);
    // 9. gate + rmsnorm (ynorm in place over y)
    gatenorm_kernel<<<MROWS, 256, 0, stream>>>(zxbc, gamma, zxbc);
    // 10. out = ynorm @ Wout   (dbuf pipeline, K=2048; 1D grid = 128 mt * 4 nt)
    gemm_db<float><<<128 * (DM / 128), 256, 0, stream>>>(
        zxbc + DI, WoutT, out, DM, DI, ZXW, DM);
}

// Round 14
// 348.447 us; speedup vs baseline: 1.2029x; 1.0522x over previous
//
#include <hip/hip_runtime.h>
#include <hip/hip_bf16.h>

// Mamba2 block forward. B=4 L=4096 D_MODEL=512 D_INNER=2048 H=8 P=256 N=64
// CHUNK=256 C=16 CONV_DIM=2176.
// Round 14: ssd_y v4 — p-split (ph in {0,1}): per block 64l x 128p. LDS
// 48.5->32.5KB, acc 64->32 AGPR (under the 128-reg cliff) -> 4 blocks/CU,
// 16 waves (was 3/7). Same barrier skeleton as r11/r13. Grid 2048->4096,
// all 8 blocks of a chunk on one XCD. Rest identical to r13.

#define BB 4
#define LL 4096
#define DM 512
#define DI 2048
#define NH 8
#define HD 256
#define DS 64
#define DCONV 4
#define CHK 256
#define NC 16
#define CONVD 2176
#define MROWS (BB*LL)    // 16384
#define ZXW (DI + CONVD) // 4224

typedef __hip_bfloat16 bf16;
typedef short s8 __attribute__((ext_vector_type(8)));   // 8 bf16 (4 VGPRs)
typedef float f4 __attribute__((ext_vector_type(4)));   // MFMA acc

__device__ __forceinline__ f4 mfma16(s8 a, s8 b, f4 c) {
    return __builtin_amdgcn_mfma_f32_16x16x32_bf16(a, b, c, 0, 0, 0);
}

__device__ __forceinline__ void gload16(const bf16* g, bf16* l) {
    __builtin_amdgcn_global_load_lds(
        (const __attribute__((address_space(1))) void*)g,
        (__attribute__((address_space(3))) void*)l, 16, 0, 0);
}

__device__ __forceinline__ float ldf(const float* p) { return *p; }
__device__ __forceinline__ float ldf(const bf16* p) { return __bfloat162float(*p); }
__device__ __forceinline__ void stf(float* p, float v) { *p = v; }
__device__ __forceinline__ void stf(bf16* p, float v) { *p = __float2bfloat16(v); }

// ---------------- f32 -> bf16 cast (8/thread) ----------------
__global__ void cast_bf16_kernel(const float* __restrict__ in, bf16* __restrict__ out) {
    long i8 = ((long)blockIdx.x * 256 + threadIdx.x) * 8;
    float4 a = *(const float4*)&in[i8];
    float4 b = *(const float4*)&in[i8 + 4];
    bf16 v[8];
    v[0] = __float2bfloat16(a.x); v[1] = __float2bfloat16(a.y);
    v[2] = __float2bfloat16(a.z); v[3] = __float2bfloat16(a.w);
    v[4] = __float2bfloat16(b.x); v[5] = __float2bfloat16(b.y);
    v[6] = __float2bfloat16(b.z); v[7] = __float2bfloat16(b.w);
    *(uint4*)&out[i8] = *(uint4*)v;
}

// ---------------- f32 [K][N] -> bf16 [N][K] transpose-cast (weights) ----------------
__global__ void tcast_kernel(const float* __restrict__ in, bf16* __restrict__ out,
                             int K, int N) {
    __shared__ float tile[64][65];
    int t = threadIdx.x;
    int n0 = blockIdx.x * 64, k0 = blockIdx.y * 64;
#pragma unroll
    for (int i = 0; i < 16; i++) {
        int u = t + i * 256; int kr = u >> 6, nc = u & 63;
        tile[kr][nc] = in[(long)(k0 + kr) * N + n0 + nc];
    }
    __syncthreads();
#pragma unroll
    for (int i = 0; i < 16; i++) {
        int u = t + i * 256; int nr = u >> 6, kc = u & 63;
        out[(long)(n0 + nr) * K + k0 + kc] = __float2bfloat16(tile[kc][nr]);
    }
}

// ---------------- gemm_sb: single-buffered 128^2, 4 blocks/CU ----------------
template <typename TC>
__global__ __launch_bounds__(256, 4) void gemm_sb(const bf16* __restrict__ A,
                                                  const bf16* __restrict__ BT,
                                                  TC* __restrict__ C, int N, int K,
                                                  int lda, int ldc) {
    __shared__ __align__(16) char smem[34816];  // staging 32KB | bf16 C-epilogue 34KB
    bf16 (*At)[64] = (bf16(*)[64])smem;
    bf16 (*Bt)[64] = (bf16(*)[64])(smem + 16384);
    const int t = threadIdx.x, lane = t & 63, w = t >> 6;
    const int wr = w >> 1, wc = w & 1;
    const int bid = blockIdx.x;
    const int idx = bid >> 3;
    const int mt = (bid & 7) * 16 + (idx & 15);   // nMt = 128 fixed
    const int nt = idx >> 4;
    const long m0 = (long)mt * 128;
    const int n0 = nt * 128;
    const int lrow = lane >> 3, lblk = lane & 7;
    f4 acc[4][4];
#pragma unroll
    for (int mi = 0; mi < 4; mi++)
#pragma unroll
        for (int ni = 0; ni < 4; ni++) acc[mi][ni] = (f4){0.f, 0.f, 0.f, 0.f};

    for (int k0 = 0; k0 < K; k0 += 64) {
#pragma unroll
        for (int i = 0; i < 4; i++) {
            int rbase = w * 32 + i * 8;
            int row = rbase + lrow;
            int kb = (lblk ^ (row & 7)) << 3;   // source k-block, pre-swizzled
            gload16(&A[(m0 + row) * (long)lda + k0 + kb], &At[rbase][0]);
            gload16(&BT[((long)n0 + row) * K + k0 + kb], &Bt[rbase][0]);
        }
        __syncthreads();
        __builtin_amdgcn_s_setprio(1);
#pragma unroll
        for (int ks = 0; ks < 2; ks++) {
            int k8 = ks * 4 + (lane >> 4);
            s8 af[4], bfr[4];
#pragma unroll
            for (int mi = 0; mi < 4; mi++) {
                int row = wr * 64 + mi * 16 + (lane & 15);
                af[mi] = *(const s8*)&At[row][(k8 ^ (row & 7)) << 3];
            }
#pragma unroll
            for (int ni = 0; ni < 4; ni++) {
                int row = wc * 64 + ni * 16 + (lane & 15);
                bfr[ni] = *(const s8*)&Bt[row][(k8 ^ (row & 7)) << 3];
            }
#pragma unroll
            for (int mi = 0; mi < 4; mi++)
#pragma unroll
                for (int ni = 0; ni < 4; ni++)
                    acc[mi][ni] = mfma16(af[mi], bfr[ni], acc[mi][ni]);
        }
        __builtin_amdgcn_s_setprio(0);
        __syncthreads();
    }
    if constexpr (sizeof(TC) == 2) {
        bf16 (*Ct)[136] = (bf16(*)[136])smem;
#pragma unroll
        for (int mi = 0; mi < 4; mi++)
#pragma unroll
            for (int ni = 0; ni < 4; ni++)
#pragma unroll
                for (int r = 0; r < 4; r++)
                    Ct[wr * 64 + mi * 16 + (lane >> 4) * 4 + r]
                      [wc * 64 + ni * 16 + (lane & 15)] =
                        __float2bfloat16(acc[mi][ni][r]);
        __syncthreads();
#pragma unroll
        for (int i = 0; i < 8; i++) {
            int u = t + i * 256; int row = u >> 4, j = u & 15;
            *(uint4*)&C[(m0 + row) * (long)ldc + n0 + j * 8] = *(uint4*)&Ct[row][j * 8];
        }
    } else {
#pragma unroll
        for (int mi = 0; mi < 4; mi++)
#pragma unroll
            for (int ni = 0; ni < 4; ni++)
#pragma unroll
                for (int r = 0; r < 4; r++)
                    stf(&C[(m0 + wr * 64 + mi * 16 + (lane >> 4) * 4 + r) * (long)ldc +
                           n0 + wc * 64 + ni * 16 + (lane & 15)], acc[mi][ni][r]);
    }
}

// ---------------- gemm_db: 2-phase dbuf 128^2 — used for Wout (K=2048) ----------------
template <typename TC>
__global__ __launch_bounds__(256) void gemm_db(const bf16* __restrict__ A,
                                               const bf16* __restrict__ BT,
                                               TC* __restrict__ C, int N, int K,
                                               int lda, int ldc) {
    __shared__ __align__(16) char smem[65536];
    bf16 (*At)[128][64] = (bf16(*)[128][64])smem;
    bf16 (*Bt)[128][64] = (bf16(*)[128][64])(smem + 32768);
    const int t = threadIdx.x, lane = t & 63, w = t >> 6;
    const int wr = w >> 1, wc = w & 1;
    const int bid = blockIdx.x;
    const int idx = bid >> 3;
    const int nNt = N >> 7;
    const int nt = idx % nNt;                       // nt fastest
    const int mt = (bid & 7) * 16 + (idx / nNt);    // nMt = 128 fixed
    const long m0 = (long)mt * 128;
    const int n0 = nt * 128;
    const int lrow = lane >> 3, lblk = lane & 7;
    const int KT = K >> 6;
    f4 acc[4][4];
#pragma unroll
    for (int mi = 0; mi < 4; mi++)
#pragma unroll
        for (int ni = 0; ni < 4; ni++) acc[mi][ni] = (f4){0.f, 0.f, 0.f, 0.f};

    auto STAGE = [&](int bu, int kt) {
        int k0 = kt << 6;
#pragma unroll
        for (int i = 0; i < 4; i++) {
            int rbase = w * 32 + i * 8;
            int row = rbase + lrow;
            int kb = (lblk ^ (row & 7)) << 3;
            gload16(&A[(m0 + row) * (long)lda + k0 + kb], &At[bu][rbase][0]);
            gload16(&BT[((long)n0 + row) * K + k0 + kb], &Bt[bu][rbase][0]);
        }
    };

    STAGE(0, 0);
    int bu = 0;
    for (int kt = 0; kt < KT; kt++) {
        if (kt + 1 < KT) {
            STAGE(bu ^ 1, kt + 1);
            asm volatile("s_waitcnt vmcnt(8)" ::: "memory");
        } else {
            asm volatile("s_waitcnt vmcnt(0)" ::: "memory");
        }
        __builtin_amdgcn_sched_barrier(0);
        __builtin_amdgcn_s_barrier();
        __builtin_amdgcn_s_setprio(1);
#pragma unroll
        for (int ks = 0; ks < 2; ks++) {
            int k8 = ks * 4 + (lane >> 4);
            s8 af[4], bfr[4];
#pragma unroll
            for (int mi = 0; mi < 4; mi++) {
                int row = wr * 64 + mi * 16 + (lane & 15);
                af[mi] = *(const s8*)&At[bu][row][(k8 ^ (row & 7)) << 3];
            }
#pragma unroll
            for (int ni = 0; ni < 4; ni++) {
                int row = wc * 64 + ni * 16 + (lane & 15);
                bfr[ni] = *(const s8*)&Bt[bu][row][(k8 ^ (row & 7)) << 3];
            }
#pragma unroll
            for (int mi = 0; mi < 4; mi++)
#pragma unroll
                for (int ni = 0; ni < 4; ni++)
                    acc[mi][ni] = mfma16(af[mi], bfr[ni], acc[mi][ni]);
        }
        __builtin_amdgcn_s_setprio(0);
        __builtin_amdgcn_s_barrier();
        bu ^= 1;
    }
    __syncthreads();
    if constexpr (sizeof(TC) == 2) {
        bf16 (*Ct)[136] = (bf16(*)[136])smem;
#pragma unroll
        for (int mi = 0; mi < 4; mi++)
#pragma unroll
            for (int ni = 0; ni < 4; ni++)
#pragma unroll
                for (int r = 0; r < 4; r++)
                    Ct[wr * 64 + mi * 16 + (lane >> 4) * 4 + r]
                      [wc * 64 + ni * 16 + (lane & 15)] =
                        __float2bfloat16(acc[mi][ni][r]);
        __syncthreads();
#pragma unroll
        for (int i = 0; i < 8; i++) {
            int u = t + i * 256; int row = u >> 4, j = u & 15;
            *(uint4*)&C[(m0 + row) * (long)ldc + n0 + j * 8] = *(uint4*)&Ct[row][j * 8];
        }
    } else {
        // f32 LDS-staged epilogue: two 64-row passes, 16B coalesced stores
        float (*Ctf)[132] = (float(*)[132])smem;   // 64*132*4 = 33.8KB
#pragma unroll
        for (int pass = 0; pass < 2; pass++) {
            if (wr == pass) {
#pragma unroll
                for (int mi = 0; mi < 4; mi++)
#pragma unroll
                    for (int ni = 0; ni < 4; ni++)
#pragma unroll
                        for (int r = 0; r < 4; r++)
                            Ctf[mi * 16 + (lane >> 4) * 4 + r]
                               [wc * 64 + ni * 16 + (lane & 15)] = acc[mi][ni][r];
            }
            __syncthreads();
#pragma unroll
            for (int i = 0; i < 8; i++) {
                int u = t + i * 256; int row = u >> 5, q = u & 31;
                *(float4*)&C[(m0 + pass * 64 + row) * (long)ldc + n0 + q * 4] =
                    *(float4*)&Ctf[row][q * 4];
            }
            __syncthreads();
        }
    }
}

// ---------------- dt = softplus(inputs @ Wdt + bias) ----------------
__global__ void dt_kernel(const float* __restrict__ inp, const float* __restrict__ Wdt,
                          const float* __restrict__ dt_bias, float* __restrict__ dtb) {
    __shared__ float wlds[DM * NH];  // 16 KB
    int t = threadIdx.x;
#pragma unroll
    for (int i = 0; i < 16; i++) wlds[t + i * 256] = Wdt[t + i * 256];
    __syncthreads();
    int idx = blockIdx.x * 256 + t;
    int h = idx & 7;
    long row = idx >> 3;
    const float* ir = inp + row * DM;
    float acc = 0.f;
    for (int k = 0; k < DM; k += 4) {
        float4 a = *(const float4*)&ir[k];
        acc += a.x * wlds[k * 8 + h] + a.y * wlds[(k + 1) * 8 + h]
             + a.z * wlds[(k + 2) * 8 + h] + a.w * wlds[(k + 3) * 8 + h];
    }
    acc += dt_bias[h];
    float sp = acc > 20.f ? acc : log1pf(expf(acc));
    dtb[idx] = sp;
}

// ---------------- conv_x: conv(4)+silu+*dt over x channels, writes xdtT ----------------
__global__ __launch_bounds__(256) void conv_x(const bf16* __restrict__ zxbc,
                                              const float* __restrict__ ck,
                                              const float* __restrict__ dtb,
                                              bf16* __restrict__ xdtT) {
    __shared__ __align__(16) bf16 in_lds[67][72];
    __shared__ __align__(16) bf16 out_lds[64][64];
    __shared__ float dts[64];
    const int bid = blockIdx.x;
    const int ct = bid & 31, lt = (bid >> 5) & 63, b = bid >> 11;
    const int t = threadIdx.x;
    const int l0 = lt * 64;
    const long brow = (long)b * LL;
    const int h = ct >> 2;

#pragma unroll
    for (int i = 0; i < 3; i++) {
        int u = t + i * 256;
        if (u < 536) {
            int r = u >> 3, c8 = (u & 7) * 8;
            int gl = l0 - 3 + r;
            uint4 v = (gl >= 0)
                ? *(const uint4*)&zxbc[(brow + gl) * ZXW + DI + ct * 64 + c8]
                : (uint4){0, 0, 0, 0};
            *(uint4*)&in_lds[r][c8] = v;
        }
    }
    if (t < 64) dts[t] = dtb[(brow + l0 + t) * NH + h];
    __syncthreads();

    const int ch = t & 63, w = t >> 6;
    const int gch = ct * 64 + ch;
    float k0 = ck[0 * CONVD + gch], k1 = ck[1 * CONVD + gch];
    float k2 = ck[2 * CONVD + gch], k3 = ck[3 * CONVD + gch];
    float w0 = __bfloat162float(in_lds[w * 16 + 0][ch]);
    float w1 = __bfloat162float(in_lds[w * 16 + 1][ch]);
    float w2 = __bfloat162float(in_lds[w * 16 + 2][ch]);
    bf16 o[16];
#pragma unroll
    for (int i = 0; i < 16; i++) {
        float w3 = __bfloat162float(in_lds[w * 16 + i + 3][ch]);
        float v = w0 * k0 + w1 * k1 + w2 * k2 + w3 * k3;
        float s = v / (1.f + __expf(-v));
        o[i] = __float2bfloat16(s * dts[w * 16 + i]);
        w0 = w1; w1 = w2; w2 = w3;
    }
#pragma unroll
    for (int j = 0; j < 2; j++) {
        int blk = w * 2 + j;
        *(uint4*)&out_lds[ch][((blk ^ (ch & 7)) << 3)] = *(uint4*)&o[j * 8];
    }
    __syncthreads();
#pragma unroll
    for (int i = 0; i < 2; i++) {
        int u = t + i * 256;
        int chr = u >> 3, l8 = u & 7;
        uint4 v = *(const uint4*)&out_lds[chr][((l8 ^ (chr & 7)) << 3)];
        *(uint4*)&xdtT[((long)b * DI + ct * 64 + chr) * LL + l0 + l8 * 8] = v;
    }
}

// ---------------- conv_bc: conv+silu for b/c channels ----------------
__global__ void conv_bc(const bf16* __restrict__ zxbc, const float* __restrict__ ck,
                        bf16* __restrict__ bm, bf16* __restrict__ cm) {
    long idx = (long)blockIdx.x * 256 + threadIdx.x;
    if (idx >= (long)MROWS * 128 / 8) return;
    long e0 = idx * 8;
    int ch = (int)(e0 & 127);
    long bl = e0 >> 7;
    int l = (int)(bl & (LL - 1));
    float acc[8] = {};
#pragma unroll
    for (int k = 0; k < DCONV; k++) {
        int ls = l - 3 + k;
        if (ls >= 0) {
            bf16 v[8];
            *(uint4*)v = *(const uint4*)&zxbc[(bl - l + ls) * ZXW + 2 * DI + ch];
            float4 c0 = *(const float4*)&ck[k * CONVD + DI + ch];
            float4 c1 = *(const float4*)&ck[k * CONVD + DI + ch + 4];
            acc[0] += __bfloat162float(v[0]) * c0.x;
            acc[1] += __bfloat162float(v[1]) * c0.y;
            acc[2] += __bfloat162float(v[2]) * c0.z;
            acc[3] += __bfloat162float(v[3]) * c0.w;
            acc[4] += __bfloat162float(v[4]) * c1.x;
            acc[5] += __bfloat162float(v[5]) * c1.y;
            acc[6] += __bfloat162float(v[6]) * c1.z;
            acc[7] += __bfloat162float(v[7]) * c1.w;
        }
    }
    bf16 o[8];
#pragma unroll
    for (int j = 0; j < 8; j++) {
        float s = acc[j] / (1.f + __expf(-acc[j]));
        o[j] = __float2bfloat16(s);
    }
    if (ch < DS) *(uint4*)&bm[bl * DS + ch] = *(uint4*)o;
    else         *(uint4*)&cm[bl * DS + (ch - DS)] = *(uint4*)o;
}

// ---------------- per-(b,h,c) cumsum of a*dt ----------------
__global__ void cumsum_kernel(const float* __restrict__ dtb, const float* __restrict__ a_log,
                              float* __restrict__ cumA, float* __restrict__ csum) {
    int t = blockIdx.x * 256 + threadIdx.x;  // t = b*128 + h*16 + c
    if (t >= BB * NH * NC) return;
    int c = t & 15, h = (t >> 4) & 7, b = t >> 7;
    float a = -expf(a_log[h]);
    long base_l = (long)b * LL + (long)c * CHK;
    float s = 0.f;
    long obase = (long)t * CHK;
    for (int i = 0; i < CHK; i++) {
        s += a * dtb[(base_l + i) * NH + h];
        cumA[obase + i] = s;
    }
    csum[t] = s;
}

// ---------------- states via MFMA: st[p][n] = sum_l x[l,p]*b[l,n]*dec[l] ----------------
__global__ __launch_bounds__(256, 4) void states_mfma(
        const bf16* __restrict__ bmat, const bf16* __restrict__ xdtT,
        const float* __restrict__ cumA, const float* __restrict__ csum,
        bf16* __restrict__ st) {
    __shared__ __align__(16) bf16 XT[256][72];
    __shared__ __align__(16) bf16 BT[64][72];
    const int z = blockIdx.x;  // b*128 + c*8 + h
    const int h = z & 7, c = (z >> 3) & 15, b = z >> 7;
    const long blr = (long)b * LL + (long)c * CHK;
    const int bhc = (b * NH + h) * NC + c;
    const float A = csum[bhc];
    const int t = threadIdx.x, lane = t & 63, w = t >> 6;
    const bf16* xrow = xdtT + ((long)b * DI + h * HD) * LL + c * CHK;
    f4 acc[4][4];
#pragma unroll
    for (int mi = 0; mi < 4; mi++)
#pragma unroll
        for (int ni = 0; ni < 4; ni++) acc[mi][ni] = (f4){0.f, 0.f, 0.f, 0.f};

    for (int lt = 0; lt < 4; lt++) {
        const int l0 = lt * 64;
#pragma unroll
        for (int i = 0; i < 2; i++) {
            int u = t + i * 256; int l = u >> 3, n8 = (u & 7) * 8;
            bf16 v[8];
            *(uint4*)v = *(const uint4*)&bmat[(blr + l0 + l) * DS + n8];
            float d = __expf(A - cumA[(long)bhc * CHK + l0 + l]);
#pragma unroll
            for (int j = 0; j < 8; j++) {
                int n = n8 + j;
                BT[n][l ^ ((n & 7) << 3)] = __float2bfloat16(__bfloat162float(v[j]) * d);
            }
        }
#pragma unroll
        for (int i = 0; i < 8; i++) {
            int u = t + i * 256; int pp = u >> 3, s8v = u & 7;
            *(uint4*)&XT[pp][s8v * 8] =
                *(const uint4*)&xrow[(long)pp * LL + l0 + ((s8v ^ (pp & 7)) << 3)];
        }
        __syncthreads();
        __builtin_amdgcn_s_setprio(1);
#pragma unroll
        for (int ks = 0; ks < 2; ks++) {
            int col = ks * 32 + (lane >> 4) * 8;
            s8 af[4], bx[4];
#pragma unroll
            for (int mi = 0; mi < 4; mi++) {
                int n = mi * 16 + (lane & 15);
                af[mi] = *(const s8*)&BT[n][col ^ ((n & 7) << 3)];
            }
#pragma unroll
            for (int ni = 0; ni < 4; ni++) {
                int p = w * 64 + ni * 16 + (lane & 15);
                bx[ni] = *(const s8*)&XT[p][col ^ ((p & 7) << 3)];
            }
#pragma unroll
            for (int mi = 0; mi < 4; mi++)
#pragma unroll
                for (int ni = 0; ni < 4; ni++)
                    acc[mi][ni] = mfma16(af[mi], bx[ni], acc[mi][ni]);
        }
        __builtin_amdgcn_s_setprio(0);
        __syncthreads();
    }
    bf16* so = st + (long)z * (HD * DS);
#pragma unroll
    for (int mi = 0; mi < 4; mi++)
#pragma unroll
        for (int ni = 0; ni < 4; ni++) {
            int p = w * 64 + ni * 16 + (lane & 15);
            int n0 = mi * 16 + (lane >> 4) * 4;
            bf16 vv[4];
#pragma unroll
            for (int r = 0; r < 4; r++) vv[r] = __float2bfloat16(acc[mi][ni][r]);
            *(uint2*)&so[p * 64 + n0] = *(uint2*)vv;
        }
}

// ---------------- serial chunk scan (in place, bf16, f32 accum in regs) ----------------
__global__ void scan_kernel(bf16* __restrict__ st, const float* __restrict__ csum) {
    long idx = (long)blockIdx.x * 256 + threadIdx.x;
    int pn = (int)(idx & 16383);
    int h = (int)((idx >> 14) & 7);
    int b = (int)(idx >> 17);
    float S = 0.f;
    for (int c = 0; c < NC; c++) {
        long si = (((long)(b * NC + c) * NH + h) * (HD * DS)) + pn;
        float chunk = __bfloat162float(st[si]);
        st[si] = __float2bfloat16(S);
        S = S * __expf(csum[(b * NH + h) * NC + c]) + chunk;
    }
}

// ---------------- fused SSD y via MFMA (v4: p-split, 64l x 128p / block) ----------------
__global__ __launch_bounds__(256, 4) void ssd_y_mfma(
        const bf16* __restrict__ bmat, const bf16* __restrict__ cmat,
        const bf16* __restrict__ xdtT, const bf16* __restrict__ st,
        const float* __restrict__ cumA, bf16* __restrict__ y, int ldy) {
    __shared__ __align__(16) bf16 cT[64][64];
    __shared__ __align__(16) bf16 bW[64][64];
    __shared__ __align__(16) bf16 XTt[128][64];   // 16KB (p-local rows)
    __shared__ float cumL[64], cumS[64];

    const int t = threadIdx.x, lane = t & 63, w = t >> 6;
    // XCD swizzle, grid = 4096: all 8 blocks (4lt x 2ph) of a chunk on one XCD
    const int bid0 = blockIdx.x;
    const int bid = (bid0 & 7) * 512 + (bid0 >> 3);
    const int zt = bid >> 3, lt = (bid >> 1) & 3, ph = bid & 1;
    const int h = zt & 7, c = (zt >> 3) & 15, b = zt >> 7;
    const long blr = (long)b * LL + (long)c * CHK;
    const int bhc = (b * NH + h) * NC + c;
    const int l0 = lt * 64;
    const bf16* xrow = xdtT + ((long)b * DI + h * HD + ph * 128) * LL + c * CHK;

#pragma unroll
    for (int i = 0; i < 2; i++) {
        int u = t + i * 256; int row = u >> 3, pb = u & 7;
        *(uint4*)&cT[row][pb * 8] =
            *(const uint4*)&cmat[(blr + l0 + row) * DS + ((pb ^ (row & 7)) << 3)];
    }
    if (t < 64) cumL[t] = cumA[(long)bhc * CHK + l0 + t];

    f4 acc[4][2];
#pragma unroll
    for (int mi = 0; mi < 4; mi++)
#pragma unroll
        for (int ni = 0; ni < 2; ni++) acc[mi][ni] = (f4){0.f, 0.f, 0.f, 0.f};
    __syncthreads();

    for (int stile = 0; stile <= lt; stile++) {
        const int s0 = stile * 64;
#pragma unroll
        for (int i = 0; i < 2; i++) {
            int u = t + i * 256; int row = u >> 3, pb = u & 7;
            *(uint4*)&bW[row][pb * 8] =
                *(const uint4*)&bmat[(blr + s0 + row) * DS + ((pb ^ (row & 7)) << 3)];
        }
        if (t < 64) cumS[t] = cumA[(long)bhc * CHK + s0 + t];
#pragma unroll
        for (int i = 0; i < 4; i++) {
            int u = t + i * 256; int pp = u >> 3, pb = u & 7;
            *(uint4*)&XTt[pp][pb * 8] =
                *(const uint4*)&xrow[(long)pp * LL + s0 + ((pb ^ (pp & 7)) << 3)];
        }
        __syncthreads();

        // W-gemm: wave w -> W rows [w*16, w*16+16) x 64 s, K=64 (n)
        f4 wacc[4];
#pragma unroll
        for (int ni = 0; ni < 4; ni++) wacc[ni] = (f4){0.f, 0.f, 0.f, 0.f};
        __builtin_amdgcn_s_setprio(1);
#pragma unroll
        for (int ks = 0; ks < 2; ks++) {
            int kb = ks * 4 + (lane >> 4);
            int arow = w * 16 + (lane & 15);
            s8 af = *(const s8*)&cT[arow][(kb ^ (arow & 7)) << 3];
#pragma unroll
            for (int ni = 0; ni < 4; ni++) {
                int brow = ni * 16 + (lane & 15);
                s8 bfr = *(const s8*)&bW[brow][(kb ^ (brow & 7)) << 3];
                wacc[ni] = mfma16(af, bfr, wacc[ni]);
            }
        }
        __builtin_amdgcn_s_setprio(0);
        __syncthreads();

        // epilogue: decay+mask -> bf16 W back into bW (swizzled scalar writes)
#pragma unroll
        for (int ni = 0; ni < 4; ni++) {
            int s_idx = ni * 16 + (lane & 15);
#pragma unroll
            for (int r = 0; r < 4; r++) {
                int l_loc = w * 16 + (lane >> 4) * 4 + r;
                bool valid = (stile < lt) || (l_loc >= s_idx);
                float val = valid ? wacc[ni][r] * __expf(cumL[l_loc] - cumS[s_idx]) : 0.f;
                bW[l_loc][(((s_idx >> 3) ^ (l_loc & 7)) << 3) + (s_idx & 7)] =
                    __float2bfloat16(val);
            }
        }
        __syncthreads();

        // Y-gemm: wave w -> 64 l x p-range [w*32, w*32+32), K=64 (s)
        __builtin_amdgcn_s_setprio(1);
#pragma unroll
        for (int ks = 0; ks < 2; ks++) {
            int kb = ks * 4 + (lane >> 4);
            s8 aw[4], bx[2];
#pragma unroll
            for (int mi = 0; mi < 4; mi++) {
                int arow = mi * 16 + (lane & 15);
                aw[mi] = *(const s8*)&bW[arow][(kb ^ (arow & 7)) << 3];
            }
#pragma unroll
            for (int ni = 0; ni < 2; ni++) {
                int p = w * 32 + ni * 16 + (lane & 15);
                bx[ni] = *(const s8*)&XTt[p][(kb ^ (p & 7)) << 3];
            }
#pragma unroll
            for (int mi = 0; mi < 4; mi++)
#pragma unroll
                for (int ni = 0; ni < 2; ni++)
                    acc[mi][ni] = mfma16(aw[mi], bx[ni], acc[mi][ni]);
        }
        __builtin_amdgcn_s_setprio(0);
        __syncthreads();
    }

    // ---- inter-chunk state tile: bW = cT*exp(cumL), XTt = st^T (this p half) ----
#pragma unroll
    for (int i = 0; i < 16; i++) {
        int u = t + i * 256; int l = u >> 6, n = u & 63;
        int pc = (((n >> 3) ^ (l & 7)) << 3) + (n & 7);
        bW[l][pc] = __float2bfloat16(__bfloat162float(cT[l][pc]) * __expf(cumL[l]));
    }
    {
        const bf16* sp = st + (long)zt * (HD * DS);
#pragma unroll
        for (int i = 0; i < 4; i++) {
            int u = t + i * 256; int row = u >> 3, pb = u & 7;
            *(uint4*)&XTt[row][pb * 8] =
                *(const uint4*)&sp[(ph * 128 + row) * DS + ((pb ^ (row & 7)) << 3)];
        }
    }
    __syncthreads();
    __builtin_amdgcn_s_setprio(1);
#pragma unroll
    for (int ks = 0; ks < 2; ks++) {
        int kb = ks * 4 + (lane >> 4);
        s8 aw[4], bx[2];
#pragma unroll
        for (int mi = 0; mi < 4; mi++) {
            int arow = mi * 16 + (lane & 15);
            aw[mi] = *(const s8*)&bW[arow][(kb ^ (arow & 7)) << 3];
        }
#pragma unroll
        for (int ni = 0; ni < 2; ni++) {
            int p = w * 32 + ni * 16 + (lane & 15);
            bx[ni] = *(const s8*)&XTt[p][(kb ^ (p & 7)) << 3];
        }
#pragma unroll
        for (int mi = 0; mi < 4; mi++)
#pragma unroll
            for (int ni = 0; ni < 2; ni++)
                acc[mi][ni] = mfma16(aw[mi], bx[ni], acc[mi][ni]);
    }
    __builtin_amdgcn_s_setprio(0);
    __syncthreads();

    // ---- epilogue: frags -> LDS [64][128] -> coalesced global ----
    bf16* Yl = (bf16*)XTt;   // 64*128*2 = 16KB
#pragma unroll
    for (int mi = 0; mi < 4; mi++)
#pragma unroll
        for (int ni = 0; ni < 2; ni++)
#pragma unroll
            for (int r = 0; r < 4; r++)
                Yl[(mi * 16 + (lane >> 4) * 4 + r) * 128 + w * 32 + ni * 16 + (lane & 15)] =
                    __float2bfloat16(acc[mi][ni][r]);
    __syncthreads();
#pragma unroll
    for (int i = 0; i < 4; i++) {
        int u = t + i * 256; int l = u >> 4, p8 = u & 15;
        *(uint4*)&y[(blr + l0 + l) * (long)ldy + h * HD + ph * 128 + p8 * 8] =
            *(uint4*)&Yl[l * 128 + p8 * 8];
    }
}

// ---------------- gate (silu(z)) + RMSNorm, strided over zxbc ----------------
__global__ void gatenorm_kernel(const bf16* __restrict__ zxbc,
                                const float* __restrict__ gamma, bf16* __restrict__ out) {
    int row = blockIdx.x;
    int tid = threadIdx.x;
    int d0 = tid * 8;
    bf16 yv[8], zv[8];
    *(uint4*)yv = *(const uint4*)&zxbc[(long)row * ZXW + DI + d0];  // y (over xbc cols)
    *(uint4*)zv = *(const uint4*)&zxbc[(long)row * ZXW + d0];       // z
    float g[8];
    float ss = 0.f;
#pragma unroll
    for (int i = 0; i < 8; i++) {
        float zf = __bfloat162float(zv[i]);
        float gate = zf / (1.f + __expf(-zf));
        float v = __bfloat162float(yv[i]) * gate;
        g[i] = v;
        ss += v * v;
    }
#pragma unroll
    for (int off = 32; off > 0; off >>= 1) ss += __shfl_down(ss, off);
    __shared__ float red[4];
    if ((tid & 63) == 0) red[tid >> 6] = ss;
    __syncthreads();
    float tot = red[0] + red[1] + red[2] + red[3];
    float scale = rsqrtf(tot / (float)DI + 1e-5f);
    float4 g0 = *(const float4*)&gamma[d0];
    float4 g1 = *(const float4*)&gamma[d0 + 4];
    bf16 o[8];
    o[0] = __float2bfloat16(g[0] * scale * g0.x);
    o[1] = __float2bfloat16(g[1] * scale * g0.y);
    o[2] = __float2bfloat16(g[2] * scale * g0.z);
    o[3] = __float2bfloat16(g[3] * scale * g0.w);
    o[4] = __float2bfloat16(g[4] * scale * g1.x);
    o[5] = __float2bfloat16(g[5] * scale * g1.y);
    o[6] = __float2bfloat16(g[6] * scale * g1.z);
    o[7] = __float2bfloat16(g[7] * scale * g1.w);
    *(uint4*)&out[(long)row * ZXW + DI + d0] = *(uint4*)o;  // ynorm in place
}

extern "C" void kernel_launch(void* const* d_in, const int* in_sizes, int n_in,
                              void* d_out, int out_size, void* d_ws, size_t ws_size,
                              hipStream_t stream) {
    const float* inputs = (const float*)d_in[0];
    const float* Wz = (const float*)d_in[1];
    const float* Wxbc = (const float*)d_in[2];
    const float* Wdt = (const float*)d_in[3];
    const float* conv_kernel = (const float*)d_in[4];
    const float* dt_bias = (const float*)d_in[5];
    const float* a_log = (const float*)d_in[6];
    const float* gamma = (const float*)d_in[7];
    const float* Wout = (const float*)d_in[8];
    float* out = (float*)d_out;

    // ---- workspace layout (~223 MiB) ----
    char* p = (char*)d_ws;
    float* dtb = (float*)p;      p += (long)MROWS * NH * 4;
    float* cumA = (float*)p;     p += (long)MROWS * NH * 4;
    float* csum = (float*)p;     p += 512 * 4;
    bf16* WzT = (bf16*)p;        p += (long)DI * DM * 2;      // [WzT;WxbcT] adjacent
    bf16* WxbcT = (bf16*)p;      p += (long)CONVD * DM * 2;   //  = [4224][512]
    bf16* WoutT = (bf16*)p;      p += (long)DM * DI * 2;
    bf16* bmat = (bf16*)p;       p += (long)MROWS * DS * 2;
    bf16* cmat = (bf16*)p;       p += (long)MROWS * DS * 2;
    bf16* inA = (bf16*)p;        p += (long)MROWS * DM * 2;   // -> st (bf16) after GEMM
    bf16* zxbc = (bf16*)p;       p += (long)MROWS * ZXW * 2;  // z|xbc -> z|y -> z|ynorm
    bf16* xdtT = (bf16*)p;       p += (long)DI * BB * LL * 2; // 67 MB
    bf16* st = inA;

    // 1. casts / weight transposes
    cast_bf16_kernel<<<MROWS * DM / 8 / 256, 256, 0, stream>>>(inputs, inA);
    tcast_kernel<<<dim3(DI / 64, DM / 64), 256, 0, stream>>>(Wz, WzT, DM, DI);
    tcast_kernel<<<dim3(CONVD / 64, DM / 64), 256, 0, stream>>>(Wxbc, WxbcT, DM, CONVD);
    tcast_kernel<<<dim3(DM / 64, DI / 64), 256, 0, stream>>>(Wout, WoutT, DI, DM);
    // 2. zxbc = inA @ [Wz | Wxbc]   (single-buffer 128^2; grid = 128 mt * 33 nt)
    gemm_sb<bf16><<<128 * (ZXW / 128), 256, 0, stream>>>(
        inA, WzT, zxbc, ZXW, DM, DM, ZXW);
    // 3. dt
    dt_kernel<<<MROWS * NH / 256, 256, 0, stream>>>(inputs, Wdt, dt_bias, dtb);
    // 4. conv x-part -> xdtT (transposed);  b/c part -> bmat/cmat
    conv_x<<<BB * 64 * 32, 256, 0, stream>>>(zxbc, conv_kernel, dtb, xdtT);
    conv_bc<<<MROWS * 128 / 8 / 256, 256, 0, stream>>>(zxbc, conv_kernel, bmat, cmat);
    // 5. cumsum
    cumsum_kernel<<<2, 256, 0, stream>>>(dtb, a_log, cumA, csum);
    // 6. per-chunk states (MFMA) -> st (bf16, over dead inA)
    states_mfma<<<BB * NC * NH, 256, 0, stream>>>(bmat, xdtT, cumA, csum, st);
    // 7. chunk scan (in place)
    scan_kernel<<<BB * NH * HD * DS / 256, 256, 0, stream>>>(st, csum);
    // 8. fused SSD y (MFMA v4, p-split) -> y cols of zxbc
    ssd_y_mfma<<<BB * NC * NH * 4 * 2, 256, 0, stream>>>(
        bmat, cmat, xdtT, st, cumA, zxbc + DI, ZXW);
    // 9. gate + rmsnorm (ynorm in place over y)
    gatenorm_kernel<<<MROWS, 256, 0, stream>>>(zxbc, gamma, zxbc);
    // 10. out = ynorm @ Wout   (dbuf pipeline, K=2048; 1D grid = 128 mt * 4 nt)
    gemm_db<float><<<128 * (DM / 128), 256, 0, stream>>>(
        zxbc + DI, WoutT, out, DM, DI, ZXW, DM);
}